// Round 11
// baseline (444.983 us; speedup 1.0000x reference)
//
#include <hip/hip_runtime.h>
#include <stdint.h>
#include <math.h>

#define NB   16384   // batch
#define DIN  2000
#define NH   500     // hidden
#define ND   64      // dim
#define NKC  256     // clusters

#define FLAG_CAP 4096
#define GAP_THR  0.002f  // sum-of-squares units; split-path dist noise ~1e-4 -> ~20x margin

typedef __attribute__((ext_vector_type(4))) float  f32x4;
typedef __attribute__((ext_vector_type(4))) double f64x4;
typedef __attribute__((ext_vector_type(8))) short  s16x8;

// ---------- bf16 helpers ----------
__device__ __forceinline__ unsigned short f2bf_rne(float v) {
  unsigned int u = __float_as_uint(v);
  u += 0x7fffu + ((u >> 16) & 1u);
  return (unsigned short)(u >> 16);
}
// fast split: hi = truncate-to-bf16, lo = truncate(v - hi). total rel err <= 2^-15
__device__ __forceinline__ void split_rtz(float v, unsigned short &hi, unsigned short &lo) {
  unsigned int u = __float_as_uint(v);
  hi = (unsigned short)(u >> 16);
  float r = v - __uint_as_float(u & 0xffff0000u);
  lo = (unsigned short)(__float_as_uint(r) >> 16);
}

// ---------- async global->LDS, 16B per lane ----------
typedef const __attribute__((address_space(1))) void* gas_t;
typedef __attribute__((address_space(3))) void* las_t;
__device__ __forceinline__ void gl_lds16(const void* g, void* l) {
  __builtin_amdgcn_global_load_lds((gas_t)g, (las_t)l, 16, 0, 0);
}

// ---------- split-pad body (grid-stride within [b0, nblk) segment) ----------
__device__ __forceinline__ void split_pad_seg(const float* __restrict__ in,
                                              unsigned short* __restrict__ hi,
                                              unsigned short* __restrict__ lo,
                                              int R, int C, int Cp, int total,
                                              int bseg, int nblk) {
  int stride = nblk * 256;
  for (int idx = bseg * 256 + threadIdx.x; idx < total; idx += stride) {
    int r = idx / Cp, c = idx - r * Cp;
    float v = (r < R && c < C) ? in[(size_t)r * C + c] : 0.f;
    if (lo) {
      unsigned short h, l; split_rtz(v, h, l);
      hi[idx] = h; lo[idx] = l;
    } else {
      hi[idx] = f2bf_rne(v);
    }
  }
}

// ---------- merged prep: split_x + 4 weight converts + flag-counter zero ----------
// block partition: [0,2048) x-split | [2048,3072) w1 | [3072,3136) w2
//                  [3136,3200) dec_w1 | [3200,4096) dec_w2
__global__ __launch_bounds__(256) void k_prep(const float* __restrict__ x,
                                              unsigned short* __restrict__ XHI,
                                              unsigned short* __restrict__ XLO,
                                              const float* __restrict__ w1,
                                              unsigned short* __restrict__ W1HI,
                                              unsigned short* __restrict__ W1LO,
                                              const float* __restrict__ w2,
                                              unsigned short* __restrict__ W2HI,
                                              unsigned short* __restrict__ W2LO,
                                              const float* __restrict__ dw1,
                                              unsigned short* __restrict__ DW1,
                                              const float* __restrict__ dw2,
                                              unsigned short* __restrict__ DW2,
                                              int* __restrict__ fcnt)
{
  const int b = blockIdx.x;
  if (b == 0 && threadIdx.x == 0) *fcnt = 0;
  if (b < 2048) {
    // x pre-split: [NB][2000] f32 -> [NB][2048] bf16 hi/lo, 8-elem chunks
    const int total = NB * 256;
    for (int idx = b * 256 + threadIdx.x; idx < total; idx += 2048 * 256) {
      int r = idx >> 8;
      int c8 = (idx & 255) << 3;
      s16x8 h8 = {0,0,0,0,0,0,0,0}, l8 = {0,0,0,0,0,0,0,0};
      if (c8 < DIN) {                        // DIN % 8 == 0: chunk fully real or fully pad
        const float* src = x + (size_t)r * DIN + c8;
        f32x4 v0 = *(const f32x4*)src;
        f32x4 v1 = *(const f32x4*)(src + 4);
#pragma unroll
        for (int j = 0; j < 4; ++j) {
          unsigned short h, l;
          split_rtz(v0[j], h, l); h8[j] = (short)h; l8[j] = (short)l;
          split_rtz(v1[j], h, l); h8[4 + j] = (short)h; l8[4 + j] = (short)l;
        }
      }
      *(s16x8*)&XHI[(size_t)idx * 8] = h8;
      *(s16x8*)&XLO[(size_t)idx * 8] = l8;
    }
  } else if (b < 3072) {
    split_pad_seg(w1, W1HI, W1LO, 500, 2000, 2048, 512 * 2048, b - 2048, 1024);
  } else if (b < 3136) {
    split_pad_seg(w2, W2HI, W2LO, 64, 500, 512, 64 * 512, b - 3072, 64);
  } else if (b < 3200) {
    split_pad_seg(dw1, DW1, nullptr, 500, 64, 64, 512 * 64, b - 3136, 64);
  } else {
    split_pad_seg(dw2, DW2, nullptr, 2000, 500, 512, 2048 * 512, b - 3200, 896);
  }
}

// ---------- GEMM: C[M,N] = A[M,K] * B[N,K]^T (+bias, epilogue) ----------
// BM = WR*32. EPI: 0 = f32 store, 1 = relu+split bf16, 2 = relu+bf16, 3 = sigmoid+f32
template<int WR, int BN, int WC, bool SPLIT, int EPI>
__global__ __launch_bounds__(256) void k_gemm(
    const unsigned short* __restrict__ Ahi, const unsigned short* __restrict__ Alo,
    const unsigned short* __restrict__ Bhi, const unsigned short* __restrict__ Blo,
    const float* __restrict__ bias, int bias_n,
    void* __restrict__ out0, void* __restrict__ out1,
    int ldA, int K, int out_ld, int store_n)
{
  constexpr int BM = WR * 32, BK = 32;
  constexpr int ACH = BM * 4;     // 16B chunks per A tile
  constexpr int BCH = BN * 4;
  __shared__ unsigned short aHi[BM * BK];
  __shared__ unsigned short aLo[SPLIT ? BM * BK : 8];
  __shared__ unsigned short bHi[BN * BK];
  __shared__ unsigned short bLo[SPLIT ? BN * BK : 8];

  const int tid  = threadIdx.x;
  const int lane = tid & 63, wave = tid >> 6;
  const int wm = wave >> 1, wn = wave & 1;
  const int lr = lane & 15, lg = lane >> 4;
  const int swz = (lr >> 1) & 3;            // read-side chunk XOR (const per lane)
  const int m0 = blockIdx.x * BM, n0 = blockIdx.y * BN;

  f32x4 acc[WR][WC];
#pragma unroll
  for (int i = 0; i < WR; ++i)
#pragma unroll
    for (int j = 0; j < WC; ++j)
#pragma unroll
      for (int r = 0; r < 4; ++r) acc[i][j][r] = 0.f;

  for (int k0 = 0; k0 < K; k0 += BK) {
    // ---- stage tiles: linear LDS dest, swizzled global source ----
#pragma unroll
    for (int j = 0; j < ACH / 256; ++j) {
      int c = (j * 4 + wave) * 64 + lane;
      int row = c >> 2;
      int ch = (c & 3) ^ ((row >> 1) & 3);
      const unsigned short* sA = Ahi + (size_t)(m0 + row) * ldA + k0 + ch * 8;
      gl_lds16(sA, (char*)aHi + c * 16);
      if constexpr (SPLIT) {
        const unsigned short* sL = Alo + (size_t)(m0 + row) * ldA + k0 + ch * 8;
        gl_lds16(sL, (char*)aLo + c * 16);
      }
    }
#pragma unroll
    for (int j = 0; j < BCH / 256; ++j) {
      int c = (j * 4 + wave) * 64 + lane;
      int row = c >> 2;
      int ch = (c & 3) ^ ((row >> 1) & 3);
      const unsigned short* sB = Bhi + (size_t)(n0 + row) * K + k0 + ch * 8;
      gl_lds16(sB, (char*)bHi + c * 16);
      if constexpr (SPLIT) {
        const unsigned short* sL = Blo + (size_t)(n0 + row) * K + k0 + ch * 8;
        gl_lds16(sL, (char*)bLo + c * 16);
      }
    }
    __syncthreads();   // compiler drains vmcnt before barrier

    // ---- fragments (swizzled ds_read) + MFMA ----
    const int fch = (lg ^ swz) << 3;        // ushort offset of this lane's k-chunk
    s16x8 ah[WR], bh[WC];
#pragma unroll
    for (int i = 0; i < WR; ++i)
      ah[i] = *(const s16x8*)&aHi[(wm * (WR * 16) + i * 16 + lr) * 32 + fch];
#pragma unroll
    for (int j = 0; j < WC; ++j)
      bh[j] = *(const s16x8*)&bHi[(wn * (WC * 16) + j * 16 + lr) * 32 + fch];
    if constexpr (SPLIT) {
      s16x8 al[WR], bl[WC];
#pragma unroll
      for (int i = 0; i < WR; ++i)
        al[i] = *(const s16x8*)&aLo[(wm * (WR * 16) + i * 16 + lr) * 32 + fch];
#pragma unroll
      for (int j = 0; j < WC; ++j)
        bl[j] = *(const s16x8*)&bLo[(wn * (WC * 16) + j * 16 + lr) * 32 + fch];
#pragma unroll
      for (int i = 0; i < WR; ++i)
#pragma unroll
        for (int j = 0; j < WC; ++j) {
          acc[i][j] = __builtin_amdgcn_mfma_f32_16x16x32_bf16(ah[i], bh[j], acc[i][j], 0, 0, 0);
          acc[i][j] = __builtin_amdgcn_mfma_f32_16x16x32_bf16(ah[i], bl[j], acc[i][j], 0, 0, 0);
          acc[i][j] = __builtin_amdgcn_mfma_f32_16x16x32_bf16(al[i], bh[j], acc[i][j], 0, 0, 0);
        }
    } else {
#pragma unroll
      for (int i = 0; i < WR; ++i)
#pragma unroll
        for (int j = 0; j < WC; ++j)
          acc[i][j] = __builtin_amdgcn_mfma_f32_16x16x32_bf16(ah[i], bh[j], acc[i][j], 0, 0, 0);
    }
    __syncthreads();
  }

  // ---- epilogue: C/D layout col=lane&15, row=(lane>>4)*4+reg ----
#pragma unroll
  for (int i = 0; i < WR; ++i) {
    int grow = m0 + wm * (WR * 16) + i * 16 + lg * 4;
#pragma unroll
    for (int j = 0; j < WC; ++j) {
      int gcol = n0 + wn * (WC * 16) + j * 16 + lr;
      float bv = (gcol < bias_n) ? bias[gcol] : 0.f;
      f32x4 v = acc[i][j];
#pragma unroll
      for (int r = 0; r < 4; ++r) {
        float val = v[r] + bv;
        int rr = grow + r;
        if constexpr (EPI == 0) {
          if (gcol < store_n) ((float*)out0)[(size_t)rr * out_ld + gcol] = val;
        } else if constexpr (EPI == 1) {
          val = fmaxf(val, 0.f);
          unsigned short h, l; split_rtz(val, h, l);
          ((unsigned short*)out0)[(size_t)rr * out_ld + gcol] = h;
          ((unsigned short*)out1)[(size_t)rr * out_ld + gcol] = l;
        } else if constexpr (EPI == 2) {
          val = fmaxf(val, 0.f);
          ((unsigned short*)out0)[(size_t)rr * out_ld + gcol] = f2bf_rne(val);
        } else {
          val = 1.f / (1.f + expf(-val));
          if (gcol < store_n) ((float*)out0)[(size_t)rr * out_ld + gcol] = val;
        }
      }
    }
  }
}

// ---------- clustering: dists, softmax(gamma), argmin -> quantized, flag close rows ----------
__global__ __launch_bounds__(256) void k_cluster(const float* __restrict__ z,
                                                 const float* __restrict__ mu,
                                                 float* __restrict__ gamma,
                                                 float* __restrict__ quant,
                                                 int* __restrict__ flag_cnt,
                                                 int* __restrict__ flag_list)
{
  __shared__ float mu_t[ND][NKC];   // 64 x 256 f32 = 64 KB, transposed for conflict-free reads
  for (int i = threadIdx.x; i < NKC * ND; i += 256) {
    int k = i >> 6, d = i & 63;
    mu_t[d][k] = mu[i];
  }
  __syncthreads();
  const int lane = threadIdx.x & 63, wave = threadIdx.x >> 6;
  for (int r4 = blockIdx.x * 16 + wave * 4; r4 < NB; r4 += gridDim.x * 16) {
    float zr[4];
#pragma unroll
    for (int r = 0; r < 4; ++r) zr[r] = z[(size_t)(r4 + r) * ND + lane];
    float ds[4][4];
#pragma unroll
    for (int r = 0; r < 4; ++r)
#pragma unroll
      for (int g = 0; g < 4; ++g) ds[r][g] = 0.f;
    for (int d = 0; d < ND; ++d) {
      f32x4 m4 = *(const f32x4*)&mu_t[d][lane << 2];   // this lane's 4 centroids
#pragma unroll
      for (int r = 0; r < 4; ++r) {
        float zd = __shfl(zr[r], d, 64);
#pragma unroll
        for (int g = 0; g < 4; ++g) {
          float t = zd - m4[g];
          ds[r][g] = fmaf(t, t, ds[r][g]);
        }
      }
    }
#pragma unroll
    for (int r = 0; r < 4; ++r) {
      int row = r4 + r;
      float bd = ds[r][0]; int bk = (lane << 2);
#pragma unroll
      for (int g = 1; g < 4; ++g)
        if (ds[r][g] < bd) { bd = ds[r][g]; bk = (lane << 2) + g; }
      for (int off = 1; off < 64; off <<= 1) {
        float od = __shfl_xor(bd, off, 64);
        int   ok = __shfl_xor(bk, off, 64);
        if (od < bd || (od == bd && ok < bk)) { bd = od; bk = ok; }  // first-index tie-break
      }
      // second-best (excluding global best index) for the flip-risk flag
      float sb = 3.4e38f;
#pragma unroll
      for (int g = 0; g < 4; ++g) {
        int kk = (lane << 2) + g;
        if (kk != bk) sb = fminf(sb, ds[r][g]);
      }
      for (int off = 1; off < 64; off <<= 1) sb = fminf(sb, __shfl_xor(sb, off, 64));
      if (lane == 0 && (sb - bd) < GAP_THR) {
        int p = atomicAdd(flag_cnt, 1);
        if (p < FLAG_CAP) flag_list[p] = row;
      }
      const float cc = -5.f / 64.f;   // DELTA / dim (z_dist is a mean)
      float e[4], s = 0.f;
#pragma unroll
      for (int g = 0; g < 4; ++g) { e[g] = expf(cc * (ds[r][g] - bd)); s += e[g]; }
      for (int off = 1; off < 64; off <<= 1) s += __shfl_xor(s, off, 64);
      float inv = 1.f / s;
      f32x4 g4 = { e[0] * inv, e[1] * inv, e[2] * inv, e[3] * inv };
      *(f32x4*)&gamma[(size_t)row * NKC + (lane << 2)] = g4;
      quant[(size_t)row * ND + lane] = mu[(size_t)bk * ND + lane];
    }
  }
}

// ---------- refine phase A: Hd[pos][512] = relu(x @ w1^T + b1) in f64 ----------
// v6: proven v3 inner loop; 8 y-tiles of 64 h-rows (short serial chain + high TLP).
__global__ __launch_bounds__(512) void k_ref_h(const float* __restrict__ x,
                                               const float* __restrict__ w1,
                                               const float* __restrict__ b1,
                                               const int* __restrict__ flag_cnt,
                                               const int* __restrict__ flag_list,
                                               double* __restrict__ Hd)
{
  __shared__ __align__(16) double xs[2][DIN];   // 32000 B
  __shared__ int rows_s[2];

  int cnt = *flag_cnt; if (cnt > FLAG_CAP) cnt = FLAG_CAP;
  const int base = blockIdx.x * 2;
  if (base >= cnt) return;
  const int tid = threadIdx.x, lane = tid & 63, wave = tid >> 6;
  const int ybase = blockIdx.y * 64;
  const int yend  = (ybase + 64 < NH) ? (ybase + 64) : NH;   // last tile: 52 rows

  if (tid < 2) rows_s[tid] = flag_list[(base + tid < cnt) ? (base + tid) : base];
  __syncthreads();
  const int row0 = rows_s[0], row1 = rows_s[1];

  // stage x rows (coalesced), convert to f64 once
  for (int c = tid; c < DIN; c += 512) {
    xs[0][c] = (double)x[(size_t)row0 * DIN + c];
    xs[1][c] = (double)x[(size_t)row1 * DIN + c];
  }
  __syncthreads();

  // h-rows of this tile; 4 per wave-iter, lanes k-parallel (proven v3 inner)
  for (int hr0 = ybase + wave * 4; hr0 < yend; hr0 += 32) {
    double a[4][2];
#pragma unroll
    for (int r = 0; r < 4; ++r) { a[r][0] = 0.0; a[r][1] = 0.0; }
    for (int c = lane; c < DIN / 4; c += 64) {          // 500 f32x4 chunks
      f64x4 x0 = *(const f64x4*)(&xs[0][c * 4]);
      f64x4 x1 = *(const f64x4*)(&xs[1][c * 4]);
#pragma unroll
      for (int r = 0; r < 4; ++r) {
        f32x4 w4 = *(const f32x4*)(w1 + (size_t)(hr0 + r) * DIN + c * 4);
#pragma unroll
        for (int j = 0; j < 4; ++j) {
          double w = (double)w4[j];
          a[r][0] = fma(w, x0[j], a[r][0]);
          a[r][1] = fma(w, x1[j], a[r][1]);
        }
      }
    }
#pragma unroll
    for (int off = 32; off; off >>= 1)
#pragma unroll
      for (int r = 0; r < 4; ++r) {
        a[r][0] += __shfl_xor(a[r][0], off, 64);
        a[r][1] += __shfl_xor(a[r][1], off, 64);
      }
    if (lane == 0) {
#pragma unroll
      for (int r = 0; r < 4; ++r) {
        double b = (double)b1[hr0 + r];
        double v0 = a[r][0] + b, v1 = a[r][1] + b;
        Hd[(size_t)(base + 0) * 512 + hr0 + r] = v0 > 0.0 ? v0 : 0.0;
        Hd[(size_t)(base + 1) * 512 + hr0 + r] = v1 > 0.0 ? v1 : 0.0;
      }
    }
  }
}

// ---------- refine phase B: z = Hd @ w2^T + b2 (f64), dist, argmin, write quant ----------
__global__ __launch_bounds__(512) void k_ref_zq(const float* __restrict__ w2,
                                                const float* __restrict__ b2,
                                                const float* __restrict__ mu,
                                                const double* __restrict__ Hd,
                                                const int* __restrict__ flag_cnt,
                                                const int* __restrict__ flag_list,
                                                float* __restrict__ quant)
{
  __shared__ double hsl[8][NH];     // 32 KB
  __shared__ float  mu_t[ND][NKC + 1];  // 65.8 KB, transposed, padded
  __shared__ double zs[8][ND];      // 4 KB
  __shared__ int    rows_s[8];

  int cnt = *flag_cnt; if (cnt > FLAG_CAP) cnt = FLAG_CAP;
  const int base = blockIdx.x * 8;
  if (base >= cnt) return;
  const int tid = threadIdx.x, lane = tid & 63, wave = tid >> 6;

  if (tid < 8) rows_s[tid] = flag_list[(base + tid < cnt) ? (base + tid) : base];
  // stage mu transposed
  for (int i = tid; i < NKC * ND; i += 512) {
    mu_t[i & 63][i >> 6] = mu[i];
  }
  // stage Hd rows: wave w <-> slot w
  {
    int pos = (base + wave < cnt) ? (base + wave) : base;
    const double* hr = Hd + (size_t)pos * 512;
    for (int i = lane; i < NH; i += 64) hsl[wave][i] = hr[i];
  }
  __syncthreads();

  // ---- z: 512 (row,dim) pairs; per wave 16 groups of 4 interleaved reductions ----
  for (int g4 = 0; g4 < 16; ++g4) {
    double a[4] = {0.0, 0.0, 0.0, 0.0};
    int q[4];
#pragma unroll
    for (int u = 0; u < 4; ++u) q[u] = g4 * 32 + u * 8 + wave;
    for (int i = lane; i < NH; i += 64) {
#pragma unroll
      for (int u = 0; u < 4; ++u) {
        int r = q[u] >> 6, d = q[u] & 63;
        a[u] = fma(hsl[r][i], (double)w2[(size_t)d * NH + i], a[u]);
      }
    }
#pragma unroll
    for (int off = 32; off; off >>= 1)
#pragma unroll
      for (int u = 0; u < 4; ++u) a[u] += __shfl_xor(a[u], off, 64);
    if (lane == 0) {
#pragma unroll
      for (int u = 0; u < 4; ++u) {
        int r = q[u] >> 6, d = q[u] & 63;
        zs[r][d] = a[u] + (double)b2[d];
      }
    }
  }
  __syncthreads();

  // ---- dist + argmin: wave <-> row; lane l owns clusters l, l+64, l+128, l+192 ----
  {
    double bd = 1.0e300; int bk = 0;
#pragma unroll
    for (int g = 0; g < 4; ++g) {
      int k = g * 64 + lane;
      double dist = 0.0;
#pragma unroll 8
      for (int d = 0; d < ND; ++d) {
        double t = zs[wave][d] - (double)mu_t[d][k];
        dist = fma(t, t, dist);
      }
      if (g == 0 || dist < bd) { bd = dist; bk = k; }   // k increases: strict < = first-index
    }
    for (int off = 1; off < 64; off <<= 1) {
      double od = __shfl_xor(bd, off, 64);
      int    ok = __shfl_xor(bk, off, 64);
      if (od < bd || (od == bd && ok < bk)) { bd = od; bk = ok; }
    }
    quant[(size_t)rows_s[wave] * ND + lane] = mu[(size_t)bk * ND + lane];
  }
}

// ---------- fc0: recon_z = [z | quantized] @ fc0_w^T + fc0_b  (f32, store bf16) ----------
__global__ __launch_bounds__(256) void k_fc0(const float* __restrict__ z, const float* __restrict__ quant,
                                             const float* __restrict__ W, const float* __restrict__ b,
                                             unsigned short* __restrict__ rz)
{
  __shared__ float Wt[2 * ND][ND];   // [128][64] transposed, 32 KB
  for (int i = threadIdx.x; i < ND * 2 * ND; i += 256) {
    int j = i >> 7;      // output index
    int ii = i & 127;    // input index
    Wt[ii][j] = W[i];
  }
  __syncthreads();
  const int lane = threadIdx.x & 63, wave = threadIdx.x >> 6;
  float bj = b[lane];
  for (int row = blockIdx.x * 4 + wave; row < NB; row += gridDim.x * 4) {
    float zv = z[(size_t)row * ND + lane];
    float qv = quant[(size_t)row * ND + lane];
    float acc = bj;
#pragma unroll 8
    for (int i = 0; i < ND; ++i) {
      acc = fmaf(__shfl(zv, i, 64), Wt[i][lane], acc);
      acc = fmaf(__shfl(qv, i, 64), Wt[ND + i][lane], acc);
    }
    rz[(size_t)row * ND + lane] = f2bf_rne(acc);
  }
}

// ---------- host ----------
extern "C" void kernel_launch(void* const* d_in, const int* in_sizes, int n_in,
                              void* d_out, int out_size, void* d_ws, size_t ws_size,
                              hipStream_t stream)
{
  const float* x      = (const float*)d_in[2];
  const float* mu     = (const float*)d_in[3];
  const float* enc_w1 = (const float*)d_in[4];
  const float* enc_b1 = (const float*)d_in[5];
  const float* enc_w2 = (const float*)d_in[6];
  const float* enc_b2 = (const float*)d_in[7];
  const float* fc0_w  = (const float*)d_in[8];
  const float* fc0_b  = (const float*)d_in[9];
  const float* dec_w1 = (const float*)d_in[10];
  const float* dec_b1 = (const float*)d_in[11];
  const float* dec_w2 = (const float*)d_in[12];
  const float* dec_b2 = (const float*)d_in[13];

  float* z_out  = (float*)d_out;
  float* q_out  = z_out + (size_t)NB * ND;
  float* g_out  = q_out + (size_t)NB * ND;
  float* rx_out = g_out + (size_t)NB * NKC;

  char* ws = (char*)d_ws;
  unsigned short* XHI  = (unsigned short*)ws; ws += (size_t)NB * 2048 * 2;
  unsigned short* XLO  = (unsigned short*)ws; ws += (size_t)NB * 2048 * 2;
  unsigned short* W1HI = (unsigned short*)ws; ws += (size_t)512 * 2048 * 2;
  unsigned short* W1LO = (unsigned short*)ws; ws += (size_t)512 * 2048 * 2;
  unsigned short* W2HI = (unsigned short*)ws; ws += (size_t)64 * 512 * 2;
  unsigned short* W2LO = (unsigned short*)ws; ws += (size_t)64 * 512 * 2;
  unsigned short* DW1  = (unsigned short*)ws; ws += (size_t)512 * 64 * 2;
  unsigned short* DW2  = (unsigned short*)ws; ws += (size_t)2048 * 512 * 2;
  unsigned short* HHI  = (unsigned short*)ws; ws += (size_t)NB * 512 * 2;
  unsigned short* HLO  = (unsigned short*)ws; ws += (size_t)NB * 512 * 2;
  unsigned short* H2   = (unsigned short*)ws; ws += (size_t)NB * 512 * 2;
  unsigned short* RZ   = (unsigned short*)ws; ws += (size_t)NB * ND * 2;
  int* FCNT = (int*)ws; ws += 256;                 // keep alignment
  int* FLST = (int*)ws; ws += (size_t)FLAG_CAP * 4;
  // Hd aliases XHI (dead after GEMM1): FLAG_CAP x 512 f64 = 16.8 MB << 67 MB
  double* Hd = (double*)XHI;

  // merged input conversion (+ zero padding + flag-counter zero)
  k_prep<<<4096, 256, 0, stream>>>(x, XHI, XLO, enc_w1, W1HI, W1LO,
                                   enc_w2, W2HI, W2LO, dec_w1, DW1, dec_w2, DW2, FCNT);

  // GEMM1: h = relu(x @ w1^T + b1), split 3-pass; BM=64 -> 1024 blocks = 4/CU
  dim3 g1(NB / 64, 4);
  k_gemm<2, 128, 4, true, 1><<<g1, 256, 0, stream>>>(
      XHI, XLO, W1HI, W1LO, enc_b1, 500, HHI, HLO, 2048, 2048, 512, 512);
  // GEMM2: z = h @ w2^T + b2, split 3-pass, f32 out; BM=64
  dim3 g2(NB / 64, 1);
  k_gemm<2, 64, 2, true, 0><<<g2, 256, 0, stream>>>(
      HHI, HLO, W2HI, W2LO, enc_b2, 64, z_out, nullptr, 512, 512, 64, 64);
  // clustering (+ flip-risk flagging)
  k_cluster<<<256, 256, 0, stream>>>(z_out, mu, g_out, q_out, FCNT, FLST);
  // exact f64 refinement, two phases (Hd aliases XHI which is dead now)
  dim3 gh(FLAG_CAP / 2, 8);
  k_ref_h<<<gh, 512, 0, stream>>>(x, enc_w1, enc_b1, FCNT, FLST, Hd);
  k_ref_zq<<<FLAG_CAP / 8, 512, 0, stream>>>(enc_w2, enc_b2, mu, Hd, FCNT, FLST, q_out);
  // fc0
  k_fc0<<<256, 256, 0, stream>>>(z_out, q_out, fc0_w, fc0_b, RZ);
  // GEMM4: h2 = relu(recon_z @ dec_w1^T + b1), bf16; BM=64 -> 1024 blocks
  dim3 g4(NB / 64, 4);
  k_gemm<2, 128, 4, false, 2><<<g4, 256, 0, stream>>>(
      RZ, nullptr, DW1, nullptr, dec_b1, 500, H2, nullptr, 64, 64, 512, 512);
  // GEMM5: recon_x = sigmoid(h2 @ dec_w2^T + b2), bf16, f32 masked store
  dim3 g5(NB / 128, 16);
  k_gemm<4, 128, 4, false, 3><<<g5, 256, 0, stream>>>(
      H2, nullptr, DW2, nullptr, dec_b2, 2000, rx_out, nullptr, 512, 512, 2000, 2000);
}

// Round 12
// 378.840 us; speedup vs baseline: 1.1746x; 1.1746x over previous
//
#include <hip/hip_runtime.h>
#include <stdint.h>
#include <math.h>

#define NB   16384   // batch
#define DIN  2000
#define NH   500     // hidden
#define ND   64      // dim
#define NKC  256     // clusters

#define FLAG_CAP 4096
#define GAP_THR  0.002f  // sum-of-squares units; split-path dist noise ~1e-4 -> ~20x margin

typedef __attribute__((ext_vector_type(4))) float  f32x4;
typedef __attribute__((ext_vector_type(4))) double f64x4;
typedef __attribute__((ext_vector_type(8))) short  s16x8;

// ---------- bf16 helpers ----------
__device__ __forceinline__ unsigned short f2bf_rne(float v) {
  unsigned int u = __float_as_uint(v);
  u += 0x7fffu + ((u >> 16) & 1u);
  return (unsigned short)(u >> 16);
}
// fast split: hi = truncate-to-bf16, lo = truncate(v - hi). total rel err <= 2^-15
__device__ __forceinline__ void split_rtz(float v, unsigned short &hi, unsigned short &lo) {
  unsigned int u = __float_as_uint(v);
  hi = (unsigned short)(u >> 16);
  float r = v - __uint_as_float(u & 0xffff0000u);
  lo = (unsigned short)(__float_as_uint(r) >> 16);
}

// ---------- async global->LDS, 16B per lane ----------
typedef const __attribute__((address_space(1))) void* gas_t;
typedef __attribute__((address_space(3))) void* las_t;
__device__ __forceinline__ void gl_lds16(const void* g, void* l) {
  __builtin_amdgcn_global_load_lds((gas_t)g, (las_t)l, 16, 0, 0);
}

// ---------- split-pad body (grid-stride within segment) ----------
__device__ __forceinline__ void split_pad_seg(const float* __restrict__ in,
                                              unsigned short* __restrict__ hi,
                                              unsigned short* __restrict__ lo,
                                              int R, int C, int Cp, int total,
                                              int bseg, int nblk) {
  int stride = nblk * 256;
  for (int idx = bseg * 256 + threadIdx.x; idx < total; idx += stride) {
    int r = idx / Cp, c = idx - r * Cp;
    float v = (r < R && c < C) ? in[(size_t)r * C + c] : 0.f;
    if (lo) {
      unsigned short h, l; split_rtz(v, h, l);
      hi[idx] = h; lo[idx] = l;
    } else {
      hi[idx] = f2bf_rne(v);
    }
  }
}

// ---------- merged prep: 4 weight converts + flag-counter zero (x no longer pre-split) ----------
// partition: [0,1024) w1 | [1024,1088) w2 | [1088,1152) dec_w1 | [1152,2048) dec_w2
__global__ __launch_bounds__(256) void k_prep(const float* __restrict__ w1,
                                              unsigned short* __restrict__ W1HI,
                                              unsigned short* __restrict__ W1LO,
                                              const float* __restrict__ w2,
                                              unsigned short* __restrict__ W2HI,
                                              unsigned short* __restrict__ W2LO,
                                              const float* __restrict__ dw1,
                                              unsigned short* __restrict__ DW1,
                                              const float* __restrict__ dw2,
                                              unsigned short* __restrict__ DW2,
                                              int* __restrict__ fcnt)
{
  const int b = blockIdx.x;
  if (b == 0 && threadIdx.x == 0) *fcnt = 0;
  if (b < 1024) {
    split_pad_seg(w1, W1HI, W1LO, 500, 2000, 2048, 512 * 2048, b, 1024);
  } else if (b < 1088) {
    split_pad_seg(w2, W2HI, W2LO, 64, 500, 512, 64 * 512, b - 1024, 64);
  } else if (b < 1152) {
    split_pad_seg(dw1, DW1, nullptr, 500, 64, 64, 512 * 64, b - 1088, 64);
  } else {
    split_pad_seg(dw2, DW2, nullptr, 2000, 500, 512, 2048 * 512, b - 1152, 896);
  }
}

// ---------- GEMM: C[M,N] = A[M,K] * B[N,K]^T (+bias, epilogue) ----------
// BM = WR*32. AF32: A read as f32 (ldA cols, real width 2000) and split in-register
// to the SAME linear LDS layout the gl_lds path produces -> identical fragments.
// EPI: 0 = f32 store, 1 = relu+split bf16, 2 = relu+bf16, 3 = sigmoid+f32
template<int WR, int BN, int WC, bool SPLIT, bool AF32, int EPI>
__global__ __launch_bounds__(256) void k_gemm(
    const unsigned short* __restrict__ Ahi, const unsigned short* __restrict__ Alo,
    const float* __restrict__ Axf,
    const unsigned short* __restrict__ Bhi, const unsigned short* __restrict__ Blo,
    const float* __restrict__ bias, int bias_n,
    void* __restrict__ out0, void* __restrict__ out1,
    int ldA, int K, int out_ld, int store_n)
{
  constexpr int BM = WR * 32, BK = 32;
  constexpr int ACH = BM * 4;     // 16B chunks per A tile
  constexpr int BCH = BN * 4;
  __shared__ unsigned short aHi[BM * BK];
  __shared__ unsigned short aLo[SPLIT ? BM * BK : 8];
  __shared__ unsigned short bHi[BN * BK];
  __shared__ unsigned short bLo[SPLIT ? BN * BK : 8];

  const int tid  = threadIdx.x;
  const int lane = tid & 63, wave = tid >> 6;
  const int wm = wave >> 1, wn = wave & 1;
  const int lr = lane & 15, lg = lane >> 4;
  const int swz = (lr >> 1) & 3;            // read-side chunk XOR (const per lane)
  const int m0 = blockIdx.x * BM, n0 = blockIdx.y * BN;

  f32x4 acc[WR][WC];
#pragma unroll
  for (int i = 0; i < WR; ++i)
#pragma unroll
    for (int j = 0; j < WC; ++j)
#pragma unroll
      for (int r = 0; r < 4; ++r) acc[i][j][r] = 0.f;

  for (int k0 = 0; k0 < K; k0 += BK) {
    // ---- stage A: linear LDS dest, swizzled global source chunk ----
#pragma unroll
    for (int j = 0; j < ACH / 256; ++j) {
      int c = (j * 4 + wave) * 64 + lane;
      int row = c >> 2;
      int ch = (c & 3) ^ ((row >> 1) & 3);
      if constexpr (AF32) {
        int col = k0 + ch * 8;               // 8-aligned; DIN%8==0 -> chunk all-valid or all-pad
        s16x8 h8 = {0,0,0,0,0,0,0,0}, l8 = {0,0,0,0,0,0,0,0};
        if (col < DIN) {
          const float* src = Axf + (size_t)(m0 + row) * ldA + col;
          f32x4 v0 = *(const f32x4*)src;
          f32x4 v1 = *(const f32x4*)(src + 4);
#pragma unroll
          for (int q = 0; q < 4; ++q) {
            unsigned short h, l;
            split_rtz(v0[q], h, l); h8[q] = (short)h; l8[q] = (short)l;
            split_rtz(v1[q], h, l); h8[4 + q] = (short)h; l8[4 + q] = (short)l;
          }
        }
        *(s16x8*)&aHi[c * 8] = h8;
        *(s16x8*)&aLo[c * 8] = l8;
      } else {
        const unsigned short* sA = Ahi + (size_t)(m0 + row) * ldA + k0 + ch * 8;
        gl_lds16(sA, (char*)aHi + c * 16);
        if constexpr (SPLIT) {
          const unsigned short* sL = Alo + (size_t)(m0 + row) * ldA + k0 + ch * 8;
          gl_lds16(sL, (char*)aLo + c * 16);
        }
      }
    }
    // ---- stage B (always bf16 via gl_lds, pre-padded buffers) ----
#pragma unroll
    for (int j = 0; j < BCH / 256; ++j) {
      int c = (j * 4 + wave) * 64 + lane;
      int row = c >> 2;
      int ch = (c & 3) ^ ((row >> 1) & 3);
      const unsigned short* sB = Bhi + (size_t)(n0 + row) * K + k0 + ch * 8;
      gl_lds16(sB, (char*)bHi + c * 16);
      if constexpr (SPLIT) {
        const unsigned short* sL = Blo + (size_t)(n0 + row) * K + k0 + ch * 8;
        gl_lds16(sL, (char*)bLo + c * 16);
      }
    }
    __syncthreads();   // drains vmcnt + lgkmcnt before barrier

    // ---- fragments (swizzled ds_read) + MFMA ----
    const int fch = (lg ^ swz) << 3;        // ushort offset of this lane's k-chunk
    s16x8 ah[WR], bh[WC];
#pragma unroll
    for (int i = 0; i < WR; ++i)
      ah[i] = *(const s16x8*)&aHi[(wm * (WR * 16) + i * 16 + lr) * 32 + fch];
#pragma unroll
    for (int j = 0; j < WC; ++j)
      bh[j] = *(const s16x8*)&bHi[(wn * (WC * 16) + j * 16 + lr) * 32 + fch];
    if constexpr (SPLIT) {
      s16x8 al[WR], bl[WC];
#pragma unroll
      for (int i = 0; i < WR; ++i)
        al[i] = *(const s16x8*)&aLo[(wm * (WR * 16) + i * 16 + lr) * 32 + fch];
#pragma unroll
      for (int j = 0; j < WC; ++j)
        bl[j] = *(const s16x8*)&bLo[(wn * (WC * 16) + j * 16 + lr) * 32 + fch];
#pragma unroll
      for (int i = 0; i < WR; ++i)
#pragma unroll
        for (int j = 0; j < WC; ++j) {
          acc[i][j] = __builtin_amdgcn_mfma_f32_16x16x32_bf16(ah[i], bh[j], acc[i][j], 0, 0, 0);
          acc[i][j] = __builtin_amdgcn_mfma_f32_16x16x32_bf16(ah[i], bl[j], acc[i][j], 0, 0, 0);
          acc[i][j] = __builtin_amdgcn_mfma_f32_16x16x32_bf16(al[i], bh[j], acc[i][j], 0, 0, 0);
        }
    } else {
#pragma unroll
      for (int i = 0; i < WR; ++i)
#pragma unroll
        for (int j = 0; j < WC; ++j)
          acc[i][j] = __builtin_amdgcn_mfma_f32_16x16x32_bf16(ah[i], bh[j], acc[i][j], 0, 0, 0);
    }
    __syncthreads();
  }

  // ---- epilogue: C/D layout col=lane&15, row=(lane>>4)*4+reg ----
#pragma unroll
  for (int i = 0; i < WR; ++i) {
    int grow = m0 + wm * (WR * 16) + i * 16 + lg * 4;
#pragma unroll
    for (int j = 0; j < WC; ++j) {
      int gcol = n0 + wn * (WC * 16) + j * 16 + lr;
      float bv = (gcol < bias_n) ? bias[gcol] : 0.f;
      f32x4 v = acc[i][j];
#pragma unroll
      for (int r = 0; r < 4; ++r) {
        float val = v[r] + bv;
        int rr = grow + r;
        if constexpr (EPI == 0) {
          if (gcol < store_n) ((float*)out0)[(size_t)rr * out_ld + gcol] = val;
        } else if constexpr (EPI == 1) {
          val = fmaxf(val, 0.f);
          unsigned short h, l; split_rtz(val, h, l);
          ((unsigned short*)out0)[(size_t)rr * out_ld + gcol] = h;
          ((unsigned short*)out1)[(size_t)rr * out_ld + gcol] = l;
        } else if constexpr (EPI == 2) {
          val = fmaxf(val, 0.f);
          ((unsigned short*)out0)[(size_t)rr * out_ld + gcol] = f2bf_rne(val);
        } else {
          val = 1.f / (1.f + expf(-val));
          if (gcol < store_n) ((float*)out0)[(size_t)rr * out_ld + gcol] = val;
        }
      }
    }
  }
}

// ---------- clustering: dists, softmax(gamma), argmin -> quantized, flag close rows ----------
__global__ __launch_bounds__(256) void k_cluster(const float* __restrict__ z,
                                                 const float* __restrict__ mu,
                                                 float* __restrict__ gamma,
                                                 float* __restrict__ quant,
                                                 int* __restrict__ flag_cnt,
                                                 int* __restrict__ flag_list)
{
  __shared__ float mu_t[ND][NKC];   // 64 x 256 f32 = 64 KB, transposed for conflict-free reads
  for (int i = threadIdx.x; i < NKC * ND; i += 256) {
    int k = i >> 6, d = i & 63;
    mu_t[d][k] = mu[i];
  }
  __syncthreads();
  const int lane = threadIdx.x & 63, wave = threadIdx.x >> 6;
  for (int r4 = blockIdx.x * 16 + wave * 4; r4 < NB; r4 += gridDim.x * 16) {
    float zr[4];
#pragma unroll
    for (int r = 0; r < 4; ++r) zr[r] = z[(size_t)(r4 + r) * ND + lane];
    float ds[4][4];
#pragma unroll
    for (int r = 0; r < 4; ++r)
#pragma unroll
      for (int g = 0; g < 4; ++g) ds[r][g] = 0.f;
    for (int d = 0; d < ND; ++d) {
      f32x4 m4 = *(const f32x4*)&mu_t[d][lane << 2];   // this lane's 4 centroids
#pragma unroll
      for (int r = 0; r < 4; ++r) {
        float zd = __shfl(zr[r], d, 64);
#pragma unroll
        for (int g = 0; g < 4; ++g) {
          float t = zd - m4[g];
          ds[r][g] = fmaf(t, t, ds[r][g]);
        }
      }
    }
#pragma unroll
    for (int r = 0; r < 4; ++r) {
      int row = r4 + r;
      float bd = ds[r][0]; int bk = (lane << 2);
#pragma unroll
      for (int g = 1; g < 4; ++g)
        if (ds[r][g] < bd) { bd = ds[r][g]; bk = (lane << 2) + g; }
      for (int off = 1; off < 64; off <<= 1) {
        float od = __shfl_xor(bd, off, 64);
        int   ok = __shfl_xor(bk, off, 64);
        if (od < bd || (od == bd && ok < bk)) { bd = od; bk = ok; }  // first-index tie-break
      }
      // second-best (excluding global best index) for the flip-risk flag
      float sb = 3.4e38f;
#pragma unroll
      for (int g = 0; g < 4; ++g) {
        int kk = (lane << 2) + g;
        if (kk != bk) sb = fminf(sb, ds[r][g]);
      }
      for (int off = 1; off < 64; off <<= 1) sb = fminf(sb, __shfl_xor(sb, off, 64));
      if (lane == 0 && (sb - bd) < GAP_THR) {
        int p = atomicAdd(flag_cnt, 1);
        if (p < FLAG_CAP) flag_list[p] = row;
      }
      const float cc = -5.f / 64.f;   // DELTA / dim (z_dist is a mean)
      float e[4], s = 0.f;
#pragma unroll
      for (int g = 0; g < 4; ++g) { e[g] = expf(cc * (ds[r][g] - bd)); s += e[g]; }
      for (int off = 1; off < 64; off <<= 1) s += __shfl_xor(s, off, 64);
      float inv = 1.f / s;
      f32x4 g4 = { e[0] * inv, e[1] * inv, e[2] * inv, e[3] * inv };
      *(f32x4*)&gamma[(size_t)row * NKC + (lane << 2)] = g4;
      quant[(size_t)row * ND + lane] = mu[(size_t)bk * ND + lane];
    }
  }
}

// ---------- refine phase A: Hd[pos][512] = relu(x @ w1^T + b1) in f64 ----------
// v6: proven v3 inner loop; 8 y-tiles of 64 h-rows (short serial chain + high TLP).
__global__ __launch_bounds__(512) void k_ref_h(const float* __restrict__ x,
                                               const float* __restrict__ w1,
                                               const float* __restrict__ b1,
                                               const int* __restrict__ flag_cnt,
                                               const int* __restrict__ flag_list,
                                               double* __restrict__ Hd)
{
  __shared__ __align__(16) double xs[2][DIN];   // 32000 B
  __shared__ int rows_s[2];

  int cnt = *flag_cnt; if (cnt > FLAG_CAP) cnt = FLAG_CAP;
  const int base = blockIdx.x * 2;
  if (base >= cnt) return;
  const int tid = threadIdx.x, lane = tid & 63, wave = tid >> 6;
  const int ybase = blockIdx.y * 64;
  const int yend  = (ybase + 64 < NH) ? (ybase + 64) : NH;   // last tile: 52 rows

  if (tid < 2) rows_s[tid] = flag_list[(base + tid < cnt) ? (base + tid) : base];
  __syncthreads();
  const int row0 = rows_s[0], row1 = rows_s[1];

  // stage x rows (coalesced), convert to f64 once
  for (int c = tid; c < DIN; c += 512) {
    xs[0][c] = (double)x[(size_t)row0 * DIN + c];
    xs[1][c] = (double)x[(size_t)row1 * DIN + c];
  }
  __syncthreads();

  // h-rows of this tile; 4 per wave-iter, lanes k-parallel (proven v3 inner)
  for (int hr0 = ybase + wave * 4; hr0 < yend; hr0 += 32) {
    double a[4][2];
#pragma unroll
    for (int r = 0; r < 4; ++r) { a[r][0] = 0.0; a[r][1] = 0.0; }
    for (int c = lane; c < DIN / 4; c += 64) {          // 500 f32x4 chunks
      f64x4 x0 = *(const f64x4*)(&xs[0][c * 4]);
      f64x4 x1 = *(const f64x4*)(&xs[1][c * 4]);
#pragma unroll
      for (int r = 0; r < 4; ++r) {
        f32x4 w4 = *(const f32x4*)(w1 + (size_t)(hr0 + r) * DIN + c * 4);
#pragma unroll
        for (int j = 0; j < 4; ++j) {
          double w = (double)w4[j];
          a[r][0] = fma(w, x0[j], a[r][0]);
          a[r][1] = fma(w, x1[j], a[r][1]);
        }
      }
    }
#pragma unroll
    for (int off = 32; off; off >>= 1)
#pragma unroll
      for (int r = 0; r < 4; ++r) {
        a[r][0] += __shfl_xor(a[r][0], off, 64);
        a[r][1] += __shfl_xor(a[r][1], off, 64);
      }
    if (lane == 0) {
#pragma unroll
      for (int r = 0; r < 4; ++r) {
        double b = (double)b1[hr0 + r];
        double v0 = a[r][0] + b, v1 = a[r][1] + b;
        Hd[(size_t)(base + 0) * 512 + hr0 + r] = v0 > 0.0 ? v0 : 0.0;
        Hd[(size_t)(base + 1) * 512 + hr0 + r] = v1 > 0.0 ? v1 : 0.0;
      }
    }
  }
}

// ---------- refine phase B: z = Hd @ w2^T + b2 (f64), dist, argmin, write quant ----------
__global__ __launch_bounds__(512) void k_ref_zq(const float* __restrict__ w2,
                                                const float* __restrict__ b2,
                                                const float* __restrict__ mu,
                                                const double* __restrict__ Hd,
                                                const int* __restrict__ flag_cnt,
                                                const int* __restrict__ flag_list,
                                                float* __restrict__ quant)
{
  __shared__ double hsl[8][NH];     // 32 KB
  __shared__ float  mu_t[ND][NKC + 1];  // 65.8 KB, transposed, padded
  __shared__ double zs[8][ND];      // 4 KB
  __shared__ int    rows_s[8];

  int cnt = *flag_cnt; if (cnt > FLAG_CAP) cnt = FLAG_CAP;
  const int base = blockIdx.x * 8;
  if (base >= cnt) return;
  const int tid = threadIdx.x, lane = tid & 63, wave = tid >> 6;

  if (tid < 8) rows_s[tid] = flag_list[(base + tid < cnt) ? (base + tid) : base];
  // stage mu transposed
  for (int i = tid; i < NKC * ND; i += 512) {
    mu_t[i & 63][i >> 6] = mu[i];
  }
  // stage Hd rows: wave w <-> slot w
  {
    int pos = (base + wave < cnt) ? (base + wave) : base;
    const double* hr = Hd + (size_t)pos * 512;
    for (int i = lane; i < NH; i += 64) hsl[wave][i] = hr[i];
  }
  __syncthreads();

  // ---- z: 512 (row,dim) pairs; per wave 16 groups of 4 interleaved reductions ----
  for (int g4 = 0; g4 < 16; ++g4) {
    double a[4] = {0.0, 0.0, 0.0, 0.0};
    int q[4];
#pragma unroll
    for (int u = 0; u < 4; ++u) q[u] = g4 * 32 + u * 8 + wave;
    for (int i = lane; i < NH; i += 64) {
#pragma unroll
      for (int u = 0; u < 4; ++u) {
        int r = q[u] >> 6, d = q[u] & 63;
        a[u] = fma(hsl[r][i], (double)w2[(size_t)d * NH + i], a[u]);
      }
    }
#pragma unroll
    for (int off = 32; off; off >>= 1)
#pragma unroll
      for (int u = 0; u < 4; ++u) a[u] += __shfl_xor(a[u], off, 64);
    if (lane == 0) {
#pragma unroll
      for (int u = 0; u < 4; ++u) {
        int r = q[u] >> 6, d = q[u] & 63;
        zs[r][d] = a[u] + (double)b2[d];
      }
    }
  }
  __syncthreads();

  // ---- dist + argmin: wave <-> row; lane l owns clusters l, l+64, l+128, l+192 ----
  {
    double bd = 1.0e300; int bk = 0;
#pragma unroll
    for (int g = 0; g < 4; ++g) {
      int k = g * 64 + lane;
      double dist = 0.0;
#pragma unroll 8
      for (int d = 0; d < ND; ++d) {
        double t = zs[wave][d] - (double)mu_t[d][k];
        dist = fma(t, t, dist);
      }
      if (g == 0 || dist < bd) { bd = dist; bk = k; }   // k increases: strict < = first-index
    }
    for (int off = 1; off < 64; off <<= 1) {
      double od = __shfl_xor(bd, off, 64);
      int    ok = __shfl_xor(bk, off, 64);
      if (od < bd || (od == bd && ok < bk)) { bd = od; bk = ok; }
    }
    quant[(size_t)rows_s[wave] * ND + lane] = mu[(size_t)bk * ND + lane];
  }
}

// ---------- fc0: recon_z = [z | quantized] @ fc0_w^T + fc0_b  (f32, store bf16) ----------
__global__ __launch_bounds__(256) void k_fc0(const float* __restrict__ z, const float* __restrict__ quant,
                                             const float* __restrict__ W, const float* __restrict__ b,
                                             unsigned short* __restrict__ rz)
{
  __shared__ float Wt[2 * ND][ND];   // [128][64] transposed, 32 KB
  for (int i = threadIdx.x; i < ND * 2 * ND; i += 256) {
    int j = i >> 7;      // output index
    int ii = i & 127;    // input index
    Wt[ii][j] = W[i];
  }
  __syncthreads();
  const int lane = threadIdx.x & 63, wave = threadIdx.x >> 6;
  float bj = b[lane];
  for (int row = blockIdx.x * 4 + wave; row < NB; row += gridDim.x * 4) {
    float zv = z[(size_t)row * ND + lane];
    float qv = quant[(size_t)row * ND + lane];
    float acc = bj;
#pragma unroll 8
    for (int i = 0; i < ND; ++i) {
      acc = fmaf(__shfl(zv, i, 64), Wt[i][lane], acc);
      acc = fmaf(__shfl(qv, i, 64), Wt[ND + i][lane], acc);
    }
    rz[(size_t)row * ND + lane] = f2bf_rne(acc);
  }
}

// ---------- host ----------
extern "C" void kernel_launch(void* const* d_in, const int* in_sizes, int n_in,
                              void* d_out, int out_size, void* d_ws, size_t ws_size,
                              hipStream_t stream)
{
  const float* x      = (const float*)d_in[2];
  const float* mu     = (const float*)d_in[3];
  const float* enc_w1 = (const float*)d_in[4];
  const float* enc_b1 = (const float*)d_in[5];
  const float* enc_w2 = (const float*)d_in[6];
  const float* enc_b2 = (const float*)d_in[7];
  const float* fc0_w  = (const float*)d_in[8];
  const float* fc0_b  = (const float*)d_in[9];
  const float* dec_w1 = (const float*)d_in[10];
  const float* dec_b1 = (const float*)d_in[11];
  const float* dec_w2 = (const float*)d_in[12];
  const float* dec_b2 = (const float*)d_in[13];

  float* z_out  = (float*)d_out;
  float* q_out  = z_out + (size_t)NB * ND;
  float* g_out  = q_out + (size_t)NB * ND;
  float* rx_out = g_out + (size_t)NB * NKC;

  char* ws = (char*)d_ws;
  unsigned short* W1HI = (unsigned short*)ws; ws += (size_t)512 * 2048 * 2;
  unsigned short* W1LO = (unsigned short*)ws; ws += (size_t)512 * 2048 * 2;
  unsigned short* W2HI = (unsigned short*)ws; ws += (size_t)64 * 512 * 2;
  unsigned short* W2LO = (unsigned short*)ws; ws += (size_t)64 * 512 * 2;
  unsigned short* DW1  = (unsigned short*)ws; ws += (size_t)512 * 64 * 2;
  unsigned short* DW2  = (unsigned short*)ws; ws += (size_t)2048 * 512 * 2;
  unsigned short* HHI  = (unsigned short*)ws; ws += (size_t)NB * 512 * 2;
  unsigned short* HLO  = (unsigned short*)ws; ws += (size_t)NB * 512 * 2;
  unsigned short* H2   = (unsigned short*)ws; ws += (size_t)NB * 512 * 2;
  unsigned short* RZ   = (unsigned short*)ws; ws += (size_t)NB * ND * 2;
  int* FCNT = (int*)ws; ws += 256;                 // keep alignment
  int* FLST = (int*)ws; ws += (size_t)FLAG_CAP * 4;
  double* Hd = (double*)ws; ws += (size_t)FLAG_CAP * 512 * 8;   // 16.8 MB

  // merged weight conversion (+ zero padding + flag-counter zero)
  k_prep<<<2048, 256, 0, stream>>>(enc_w1, W1HI, W1LO, enc_w2, W2HI, W2LO,
                                   dec_w1, DW1, dec_w2, DW2, FCNT);

  // GEMM1: h = relu(x @ w1^T + b1), split 3-pass, A = f32 x split in-kernel
  dim3 g1(NB / 128, 4);
  k_gemm<4, 128, 4, true, true, 1><<<g1, 256, 0, stream>>>(
      nullptr, nullptr, x, W1HI, W1LO, enc_b1, 500, HHI, HLO, DIN, 2048, 512, 512);
  // GEMM2: z = h @ w2^T + b2, split 3-pass, f32 out; BM=64
  dim3 g2(NB / 64, 1);
  k_gemm<2, 64, 2, true, false, 0><<<g2, 256, 0, stream>>>(
      HHI, HLO, nullptr, W2HI, W2LO, enc_b2, 64, z_out, nullptr, 512, 512, 64, 64);
  // clustering (+ flip-risk flagging)
  k_cluster<<<256, 256, 0, stream>>>(z_out, mu, g_out, q_out, FCNT, FLST);
  // exact f64 refinement, two phases
  dim3 gh(FLAG_CAP / 2, 8);
  k_ref_h<<<gh, 512, 0, stream>>>(x, enc_w1, enc_b1, FCNT, FLST, Hd);
  k_ref_zq<<<FLAG_CAP / 8, 512, 0, stream>>>(enc_w2, enc_b2, mu, Hd, FCNT, FLST, q_out);
  // fc0
  k_fc0<<<256, 256, 0, stream>>>(z_out, q_out, fc0_w, fc0_b, RZ);
  // GEMM4: h2 = relu(recon_z @ dec_w1^T + b1), bf16; BM=128 (reverted)
  dim3 g4(NB / 128, 4);
  k_gemm<4, 128, 4, false, false, 2><<<g4, 256, 0, stream>>>(
      RZ, nullptr, nullptr, DW1, nullptr, dec_b1, 500, H2, nullptr, 64, 64, 512, 512);
  // GEMM5: recon_x = sigmoid(h2 @ dec_w2^T + b2), bf16, f32 masked store
  dim3 g5(NB / 128, 16);
  k_gemm<4, 128, 4, false, false, 3><<<g5, 256, 0, stream>>>(
      H2, nullptr, nullptr, DW2, nullptr, dec_b2, 2000, rx_out, nullptr, 512, 512, 2000, 2000);
}

// Round 13
// 372.755 us; speedup vs baseline: 1.1938x; 1.0163x over previous
//
#include <hip/hip_runtime.h>
#include <stdint.h>
#include <math.h>

#define NB   16384   // batch
#define DIN  2000
#define NH   500     // hidden
#define ND   64      // dim
#define NKC  256     // clusters

#define FLAG_CAP 4096
#define GAP_THR  0.002f  // sum-of-squares units; split-path dist noise ~1e-4 -> ~20x margin

typedef __attribute__((ext_vector_type(4))) float  f32x4;
typedef __attribute__((ext_vector_type(4))) double f64x4;
typedef __attribute__((ext_vector_type(8))) short  s16x8;

// ---------- bf16 helpers ----------
__device__ __forceinline__ unsigned short f2bf_rne(float v) {
  unsigned int u = __float_as_uint(v);
  u += 0x7fffu + ((u >> 16) & 1u);
  return (unsigned short)(u >> 16);
}
// fast split: hi = truncate-to-bf16, lo = truncate(v - hi). total rel err <= 2^-15
__device__ __forceinline__ void split_rtz(float v, unsigned short &hi, unsigned short &lo) {
  unsigned int u = __float_as_uint(v);
  hi = (unsigned short)(u >> 16);
  float r = v - __uint_as_float(u & 0xffff0000u);
  lo = (unsigned short)(__float_as_uint(r) >> 16);
}

// ---------- async global->LDS, 16B per lane ----------
typedef const __attribute__((address_space(1))) void* gas_t;
typedef __attribute__((address_space(3))) void* las_t;
__device__ __forceinline__ void gl_lds16(const void* g, void* l) {
  __builtin_amdgcn_global_load_lds((gas_t)g, (las_t)l, 16, 0, 0);
}

// ---------- split-pad body (grid-stride within segment) ----------
__device__ __forceinline__ void split_pad_seg(const float* __restrict__ in,
                                              unsigned short* __restrict__ hi,
                                              unsigned short* __restrict__ lo,
                                              int R, int C, int Cp, int total,
                                              int bseg, int nblk) {
  int stride = nblk * 256;
  for (int idx = bseg * 256 + threadIdx.x; idx < total; idx += stride) {
    int r = idx / Cp, c = idx - r * Cp;
    float v = (r < R && c < C) ? in[(size_t)r * C + c] : 0.f;
    if (lo) {
      unsigned short h, l; split_rtz(v, h, l);
      hi[idx] = h; lo[idx] = l;
    } else {
      hi[idx] = f2bf_rne(v);
    }
  }
}

// ---------- merged prep: 4 weight converts + flag-counter zero ----------
// partition: [0,1024) w1 | [1024,1088) w2 | [1088,1152) dec_w1 | [1152,2048) dec_w2
__global__ __launch_bounds__(256) void k_prep(const float* __restrict__ w1,
                                              unsigned short* __restrict__ W1HI,
                                              unsigned short* __restrict__ W1LO,
                                              const float* __restrict__ w2,
                                              unsigned short* __restrict__ W2HI,
                                              unsigned short* __restrict__ W2LO,
                                              const float* __restrict__ dw1,
                                              unsigned short* __restrict__ DW1,
                                              const float* __restrict__ dw2,
                                              unsigned short* __restrict__ DW2,
                                              int* __restrict__ fcnt)
{
  const int b = blockIdx.x;
  if (b == 0 && threadIdx.x == 0) *fcnt = 0;
  if (b < 1024) {
    split_pad_seg(w1, W1HI, W1LO, 500, 2000, 2048, 512 * 2048, b, 1024);
  } else if (b < 1088) {
    split_pad_seg(w2, W2HI, W2LO, 64, 500, 512, 64 * 512, b - 1024, 64);
  } else if (b < 1152) {
    split_pad_seg(dw1, DW1, nullptr, 500, 64, 64, 512 * 64, b - 1088, 64);
  } else {
    split_pad_seg(dw2, DW2, nullptr, 2000, 500, 512, 2048 * 512, b - 1152, 896);
  }
}

// ---------- GEMM: C[M,N] = A[M,K] * B[N,K]^T (+bias, epilogue) ----------
// BM = WR*32. BK in {32,64}: chunk swizzle ch ^= (row>>1)&(BK/8-1) (at BK=32 this
// is the proven round-12 code). AF32: A read f32 + split in-register to LDS.
// EPI: 0 = f32 store, 1 = relu+split bf16, 2 = relu+bf16, 3 = sigmoid+f32
template<int WR, int BN, int WC, bool SPLIT, bool AF32, int EPI, int BK>
__global__ __launch_bounds__(256) void k_gemm(
    const unsigned short* __restrict__ Ahi, const unsigned short* __restrict__ Alo,
    const float* __restrict__ Axf,
    const unsigned short* __restrict__ Bhi, const unsigned short* __restrict__ Blo,
    const float* __restrict__ bias, int bias_n,
    void* __restrict__ out0, void* __restrict__ out1,
    int ldA, int K, int out_ld, int store_n)
{
  constexpr int BM  = WR * 32;
  constexpr int CPR = BK / 8;          // 16B chunks per row
  constexpr int ACH = BM * CPR;        // chunks per A tile
  constexpr int BCH = BN * CPR;
  __shared__ unsigned short aHi[BM * BK];
  __shared__ unsigned short aLo[SPLIT ? BM * BK : 8];
  __shared__ unsigned short bHi[BN * BK];
  __shared__ unsigned short bLo[SPLIT ? BN * BK : 8];

  const int tid  = threadIdx.x;
  const int lane = tid & 63, wave = tid >> 6;
  const int wm = wave >> 1, wn = wave & 1;
  const int lr = lane & 15, lg = lane >> 4;
  const int swz = (lr >> 1) & (CPR - 1);    // read-side chunk XOR (const per lane)
  const int m0 = blockIdx.x * BM, n0 = blockIdx.y * BN;

  f32x4 acc[WR][WC];
#pragma unroll
  for (int i = 0; i < WR; ++i)
#pragma unroll
    for (int j = 0; j < WC; ++j)
#pragma unroll
      for (int r = 0; r < 4; ++r) acc[i][j][r] = 0.f;

  for (int k0 = 0; k0 < K; k0 += BK) {
    // ---- stage A: linear LDS dest, swizzled global source chunk ----
#pragma unroll
    for (int j = 0; j < ACH / 256; ++j) {
      int c = (j * 4 + wave) * 64 + lane;
      int row = c / CPR;
      int ch = (c & (CPR - 1)) ^ ((row >> 1) & (CPR - 1));
      if constexpr (AF32) {
        int col = k0 + ch * 8;               // 8-aligned; DIN%8==0 -> chunk all-valid or all-pad
        s16x8 h8 = {0,0,0,0,0,0,0,0}, l8 = {0,0,0,0,0,0,0,0};
        if (col < DIN) {
          const float* src = Axf + (size_t)(m0 + row) * ldA + col;
          f32x4 v0 = *(const f32x4*)src;
          f32x4 v1 = *(const f32x4*)(src + 4);
#pragma unroll
          for (int q = 0; q < 4; ++q) {
            unsigned short h, l;
            split_rtz(v0[q], h, l); h8[q] = (short)h; l8[q] = (short)l;
            split_rtz(v1[q], h, l); h8[4 + q] = (short)h; l8[4 + q] = (short)l;
          }
        }
        *(s16x8*)&aHi[c * 8] = h8;
        *(s16x8*)&aLo[c * 8] = l8;
      } else {
        const unsigned short* sA = Ahi + (size_t)(m0 + row) * ldA + k0 + ch * 8;
        gl_lds16(sA, (char*)aHi + c * 16);
        if constexpr (SPLIT) {
          const unsigned short* sL = Alo + (size_t)(m0 + row) * ldA + k0 + ch * 8;
          gl_lds16(sL, (char*)aLo + c * 16);
        }
      }
    }
    // ---- stage B (always bf16 via gl_lds, pre-padded buffers) ----
#pragma unroll
    for (int j = 0; j < BCH / 256; ++j) {
      int c = (j * 4 + wave) * 64 + lane;
      int row = c / CPR;
      int ch = (c & (CPR - 1)) ^ ((row >> 1) & (CPR - 1));
      const unsigned short* sB = Bhi + (size_t)(n0 + row) * K + k0 + ch * 8;
      gl_lds16(sB, (char*)bHi + c * 16);
      if constexpr (SPLIT) {
        const unsigned short* sL = Blo + (size_t)(n0 + row) * K + k0 + ch * 8;
        gl_lds16(sL, (char*)bLo + c * 16);
      }
    }
    __syncthreads();   // drains vmcnt + lgkmcnt before barrier

    // ---- fragments (swizzled ds_read) + MFMA, one sub-step per 32 of K ----
#pragma unroll
    for (int kk = 0; kk < BK / 32; ++kk) {
      const int fch = ((lg + 4 * kk) ^ swz) << 3;   // ushort offset of lane's k-chunk
      s16x8 ah[WR], bh[WC];
#pragma unroll
      for (int i = 0; i < WR; ++i)
        ah[i] = *(const s16x8*)&aHi[(wm * (WR * 16) + i * 16 + lr) * BK + fch];
#pragma unroll
      for (int j = 0; j < WC; ++j)
        bh[j] = *(const s16x8*)&bHi[(wn * (WC * 16) + j * 16 + lr) * BK + fch];
      if constexpr (SPLIT) {
        s16x8 al[WR], bl[WC];
#pragma unroll
        for (int i = 0; i < WR; ++i)
          al[i] = *(const s16x8*)&aLo[(wm * (WR * 16) + i * 16 + lr) * BK + fch];
#pragma unroll
        for (int j = 0; j < WC; ++j)
          bl[j] = *(const s16x8*)&bLo[(wn * (WC * 16) + j * 16 + lr) * BK + fch];
#pragma unroll
        for (int i = 0; i < WR; ++i)
#pragma unroll
          for (int j = 0; j < WC; ++j) {
            acc[i][j] = __builtin_amdgcn_mfma_f32_16x16x32_bf16(ah[i], bh[j], acc[i][j], 0, 0, 0);
            acc[i][j] = __builtin_amdgcn_mfma_f32_16x16x32_bf16(ah[i], bl[j], acc[i][j], 0, 0, 0);
            acc[i][j] = __builtin_amdgcn_mfma_f32_16x16x32_bf16(al[i], bh[j], acc[i][j], 0, 0, 0);
          }
      } else {
#pragma unroll
        for (int i = 0; i < WR; ++i)
#pragma unroll
          for (int j = 0; j < WC; ++j)
            acc[i][j] = __builtin_amdgcn_mfma_f32_16x16x32_bf16(ah[i], bh[j], acc[i][j], 0, 0, 0);
      }
    }
    __syncthreads();
  }

  // ---- epilogue: C/D layout col=lane&15, row=(lane>>4)*4+reg ----
#pragma unroll
  for (int i = 0; i < WR; ++i) {
    int grow = m0 + wm * (WR * 16) + i * 16 + lg * 4;
#pragma unroll
    for (int j = 0; j < WC; ++j) {
      int gcol = n0 + wn * (WC * 16) + j * 16 + lr;
      float bv = (gcol < bias_n) ? bias[gcol] : 0.f;
      f32x4 v = acc[i][j];
#pragma unroll
      for (int r = 0; r < 4; ++r) {
        float val = v[r] + bv;
        int rr = grow + r;
        if constexpr (EPI == 0) {
          if (gcol < store_n) ((float*)out0)[(size_t)rr * out_ld + gcol] = val;
        } else if constexpr (EPI == 1) {
          val = fmaxf(val, 0.f);
          unsigned short h, l; split_rtz(val, h, l);
          ((unsigned short*)out0)[(size_t)rr * out_ld + gcol] = h;
          ((unsigned short*)out1)[(size_t)rr * out_ld + gcol] = l;
        } else if constexpr (EPI == 2) {
          val = fmaxf(val, 0.f);
          ((unsigned short*)out0)[(size_t)rr * out_ld + gcol] = f2bf_rne(val);
        } else {
          val = 1.f / (1.f + expf(-val));
          if (gcol < store_n) ((float*)out0)[(size_t)rr * out_ld + gcol] = val;
        }
      }
    }
  }
}

// ---------- clustering: dists, softmax(gamma), argmin -> quantized, flag close rows ----------
__global__ __launch_bounds__(256) void k_cluster(const float* __restrict__ z,
                                                 const float* __restrict__ mu,
                                                 float* __restrict__ gamma,
                                                 float* __restrict__ quant,
                                                 int* __restrict__ flag_cnt,
                                                 int* __restrict__ flag_list)
{
  __shared__ float mu_t[ND][NKC];   // 64 x 256 f32 = 64 KB, transposed for conflict-free reads
  for (int i = threadIdx.x; i < NKC * ND; i += 256) {
    int k = i >> 6, d = i & 63;
    mu_t[d][k] = mu[i];
  }
  __syncthreads();
  const int lane = threadIdx.x & 63, wave = threadIdx.x >> 6;
  for (int r4 = blockIdx.x * 16 + wave * 4; r4 < NB; r4 += gridDim.x * 16) {
    float zr[4];
#pragma unroll
    for (int r = 0; r < 4; ++r) zr[r] = z[(size_t)(r4 + r) * ND + lane];
    float ds[4][4];
#pragma unroll
    for (int r = 0; r < 4; ++r)
#pragma unroll
      for (int g = 0; g < 4; ++g) ds[r][g] = 0.f;
    for (int d = 0; d < ND; ++d) {
      f32x4 m4 = *(const f32x4*)&mu_t[d][lane << 2];   // this lane's 4 centroids
#pragma unroll
      for (int r = 0; r < 4; ++r) {
        float zd = __shfl(zr[r], d, 64);
#pragma unroll
        for (int g = 0; g < 4; ++g) {
          float t = zd - m4[g];
          ds[r][g] = fmaf(t, t, ds[r][g]);
        }
      }
    }
#pragma unroll
    for (int r = 0; r < 4; ++r) {
      int row = r4 + r;
      float bd = ds[r][0]; int bk = (lane << 2);
#pragma unroll
      for (int g = 1; g < 4; ++g)
        if (ds[r][g] < bd) { bd = ds[r][g]; bk = (lane << 2) + g; }
      for (int off = 1; off < 64; off <<= 1) {
        float od = __shfl_xor(bd, off, 64);
        int   ok = __shfl_xor(bk, off, 64);
        if (od < bd || (od == bd && ok < bk)) { bd = od; bk = ok; }  // first-index tie-break
      }
      // second-best (excluding global best index) for the flip-risk flag
      float sb = 3.4e38f;
#pragma unroll
      for (int g = 0; g < 4; ++g) {
        int kk = (lane << 2) + g;
        if (kk != bk) sb = fminf(sb, ds[r][g]);
      }
      for (int off = 1; off < 64; off <<= 1) sb = fminf(sb, __shfl_xor(sb, off, 64));
      if (lane == 0 && (sb - bd) < GAP_THR) {
        int p = atomicAdd(flag_cnt, 1);
        if (p < FLAG_CAP) flag_list[p] = row;
      }
      const float cc = -5.f / 64.f;   // DELTA / dim (z_dist is a mean)
      float e[4], s = 0.f;
#pragma unroll
      for (int g = 0; g < 4; ++g) { e[g] = expf(cc * (ds[r][g] - bd)); s += e[g]; }
      for (int off = 1; off < 64; off <<= 1) s += __shfl_xor(s, off, 64);
      float inv = 1.f / s;
      f32x4 g4 = { e[0] * inv, e[1] * inv, e[2] * inv, e[3] * inv };
      *(f32x4*)&gamma[(size_t)row * NKC + (lane << 2)] = g4;
      quant[(size_t)row * ND + lane] = mu[(size_t)bk * ND + lane];
    }
  }
}

// ---------- refine phase A: Hd[pos][512] = relu(x @ w1^T + b1) in f64 ----------
__global__ __launch_bounds__(512) void k_ref_h(const float* __restrict__ x,
                                               const float* __restrict__ w1,
                                               const float* __restrict__ b1,
                                               const int* __restrict__ flag_cnt,
                                               const int* __restrict__ flag_list,
                                               double* __restrict__ Hd)
{
  __shared__ __align__(16) double xs[2][DIN];   // 32000 B
  __shared__ int rows_s[2];

  int cnt = *flag_cnt; if (cnt > FLAG_CAP) cnt = FLAG_CAP;
  const int base = blockIdx.x * 2;
  if (base >= cnt) return;
  const int tid = threadIdx.x, lane = tid & 63, wave = tid >> 6;
  const int ybase = blockIdx.y * 64;
  const int yend  = (ybase + 64 < NH) ? (ybase + 64) : NH;   // last tile: 52 rows

  if (tid < 2) rows_s[tid] = flag_list[(base + tid < cnt) ? (base + tid) : base];
  __syncthreads();
  const int row0 = rows_s[0], row1 = rows_s[1];

  // stage x rows (coalesced), convert to f64 once
  for (int c = tid; c < DIN; c += 512) {
    xs[0][c] = (double)x[(size_t)row0 * DIN + c];
    xs[1][c] = (double)x[(size_t)row1 * DIN + c];
  }
  __syncthreads();

  // h-rows of this tile; 4 per wave-iter, lanes k-parallel (proven v3 inner)
  for (int hr0 = ybase + wave * 4; hr0 < yend; hr0 += 32) {
    double a[4][2];
#pragma unroll
    for (int r = 0; r < 4; ++r) { a[r][0] = 0.0; a[r][1] = 0.0; }
    for (int c = lane; c < DIN / 4; c += 64) {          // 500 f32x4 chunks
      f64x4 x0 = *(const f64x4*)(&xs[0][c * 4]);
      f64x4 x1 = *(const f64x4*)(&xs[1][c * 4]);
#pragma unroll
      for (int r = 0; r < 4; ++r) {
        f32x4 w4 = *(const f32x4*)(w1 + (size_t)(hr0 + r) * DIN + c * 4);
#pragma unroll
        for (int j = 0; j < 4; ++j) {
          double w = (double)w4[j];
          a[r][0] = fma(w, x0[j], a[r][0]);
          a[r][1] = fma(w, x1[j], a[r][1]);
        }
      }
    }
#pragma unroll
    for (int off = 32; off; off >>= 1)
#pragma unroll
      for (int r = 0; r < 4; ++r) {
        a[r][0] += __shfl_xor(a[r][0], off, 64);
        a[r][1] += __shfl_xor(a[r][1], off, 64);
      }
    if (lane == 0) {
#pragma unroll
      for (int r = 0; r < 4; ++r) {
        double b = (double)b1[hr0 + r];
        double v0 = a[r][0] + b, v1 = a[r][1] + b;
        Hd[(size_t)(base + 0) * 512 + hr0 + r] = v0 > 0.0 ? v0 : 0.0;
        Hd[(size_t)(base + 1) * 512 + hr0 + r] = v1 > 0.0 ? v1 : 0.0;
      }
    }
  }
}

// ---------- refine phase B: z = Hd @ w2^T + b2 (f64), dist, argmin, write quant ----------
__global__ __launch_bounds__(512) void k_ref_zq(const float* __restrict__ w2,
                                                const float* __restrict__ b2,
                                                const float* __restrict__ mu,
                                                const double* __restrict__ Hd,
                                                const int* __restrict__ flag_cnt,
                                                const int* __restrict__ flag_list,
                                                float* __restrict__ quant)
{
  __shared__ double hsl[8][NH];     // 32 KB
  __shared__ float  mu_t[ND][NKC + 1];  // 65.8 KB, transposed, padded
  __shared__ double zs[8][ND];      // 4 KB
  __shared__ int    rows_s[8];

  int cnt = *flag_cnt; if (cnt > FLAG_CAP) cnt = FLAG_CAP;
  const int base = blockIdx.x * 8;
  if (base >= cnt) return;
  const int tid = threadIdx.x, lane = tid & 63, wave = tid >> 6;

  if (tid < 8) rows_s[tid] = flag_list[(base + tid < cnt) ? (base + tid) : base];
  // stage mu transposed
  for (int i = tid; i < NKC * ND; i += 512) {
    mu_t[i & 63][i >> 6] = mu[i];
  }
  // stage Hd rows: wave w <-> slot w
  {
    int pos = (base + wave < cnt) ? (base + wave) : base;
    const double* hr = Hd + (size_t)pos * 512;
    for (int i = lane; i < NH; i += 64) hsl[wave][i] = hr[i];
  }
  __syncthreads();

  // ---- z: 512 (row,dim) pairs; per wave 16 groups of 4 interleaved reductions ----
  for (int g4 = 0; g4 < 16; ++g4) {
    double a[4] = {0.0, 0.0, 0.0, 0.0};
    int q[4];
#pragma unroll
    for (int u = 0; u < 4; ++u) q[u] = g4 * 32 + u * 8 + wave;
    for (int i = lane; i < NH; i += 64) {
#pragma unroll
      for (int u = 0; u < 4; ++u) {
        int r = q[u] >> 6, d = q[u] & 63;
        a[u] = fma(hsl[r][i], (double)w2[(size_t)d * NH + i], a[u]);
      }
    }
#pragma unroll
    for (int off = 32; off; off >>= 1)
#pragma unroll
      for (int u = 0; u < 4; ++u) a[u] += __shfl_xor(a[u], off, 64);
    if (lane == 0) {
#pragma unroll
      for (int u = 0; u < 4; ++u) {
        int r = q[u] >> 6, d = q[u] & 63;
        zs[r][d] = a[u] + (double)b2[d];
      }
    }
  }
  __syncthreads();

  // ---- dist + argmin: wave <-> row; lane l owns clusters l, l+64, l+128, l+192 ----
  {
    double bd = 1.0e300; int bk = 0;
#pragma unroll
    for (int g = 0; g < 4; ++g) {
      int k = g * 64 + lane;
      double dist = 0.0;
#pragma unroll 8
      for (int d = 0; d < ND; ++d) {
        double t = zs[wave][d] - (double)mu_t[d][k];
        dist = fma(t, t, dist);
      }
      if (g == 0 || dist < bd) { bd = dist; bk = k; }   // k increases: strict < = first-index
    }
    for (int off = 1; off < 64; off <<= 1) {
      double od = __shfl_xor(bd, off, 64);
      int    ok = __shfl_xor(bk, off, 64);
      if (od < bd || (od == bd && ok < bk)) { bd = od; bk = ok; }
    }
    quant[(size_t)rows_s[wave] * ND + lane] = mu[(size_t)bk * ND + lane];
  }
}

// ---------- fc0: recon_z = [z | quantized] @ fc0_w^T + fc0_b  (f32, store bf16) ----------
__global__ __launch_bounds__(256) void k_fc0(const float* __restrict__ z, const float* __restrict__ quant,
                                             const float* __restrict__ W, const float* __restrict__ b,
                                             unsigned short* __restrict__ rz)
{
  __shared__ float Wt[2 * ND][ND];   // [128][64] transposed, 32 KB
  for (int i = threadIdx.x; i < ND * 2 * ND; i += 256) {
    int j = i >> 7;      // output index
    int ii = i & 127;    // input index
    Wt[ii][j] = W[i];
  }
  __syncthreads();
  const int lane = threadIdx.x & 63, wave = threadIdx.x >> 6;
  float bj = b[lane];
  for (int row = blockIdx.x * 4 + wave; row < NB; row += gridDim.x * 4) {
    float zv = z[(size_t)row * ND + lane];
    float qv = quant[(size_t)row * ND + lane];
    float acc = bj;
#pragma unroll 8
    for (int i = 0; i < ND; ++i) {
      acc = fmaf(__shfl(zv, i, 64), Wt[i][lane], acc);
      acc = fmaf(__shfl(qv, i, 64), Wt[ND + i][lane], acc);
    }
    rz[(size_t)row * ND + lane] = f2bf_rne(acc);
  }
}

// ---------- host ----------
extern "C" void kernel_launch(void* const* d_in, const int* in_sizes, int n_in,
                              void* d_out, int out_size, void* d_ws, size_t ws_size,
                              hipStream_t stream)
{
  const float* x      = (const float*)d_in[2];
  const float* mu     = (const float*)d_in[3];
  const float* enc_w1 = (const float*)d_in[4];
  const float* enc_b1 = (const float*)d_in[5];
  const float* enc_w2 = (const float*)d_in[6];
  const float* enc_b2 = (const float*)d_in[7];
  const float* fc0_w  = (const float*)d_in[8];
  const float* fc0_b  = (const float*)d_in[9];
  const float* dec_w1 = (const float*)d_in[10];
  const float* dec_b1 = (const float*)d_in[11];
  const float* dec_w2 = (const float*)d_in[12];
  const float* dec_b2 = (const float*)d_in[13];

  float* z_out  = (float*)d_out;
  float* q_out  = z_out + (size_t)NB * ND;
  float* g_out  = q_out + (size_t)NB * ND;
  float* rx_out = g_out + (size_t)NB * NKC;

  char* ws = (char*)d_ws;
  unsigned short* W1HI = (unsigned short*)ws; ws += (size_t)512 * 2048 * 2;
  unsigned short* W1LO = (unsigned short*)ws; ws += (size_t)512 * 2048 * 2;
  unsigned short* W2HI = (unsigned short*)ws; ws += (size_t)64 * 512 * 2;
  unsigned short* W2LO = (unsigned short*)ws; ws += (size_t)64 * 512 * 2;
  unsigned short* DW1  = (unsigned short*)ws; ws += (size_t)512 * 64 * 2;
  unsigned short* DW2  = (unsigned short*)ws; ws += (size_t)2048 * 512 * 2;
  unsigned short* HHI  = (unsigned short*)ws; ws += (size_t)NB * 512 * 2;
  unsigned short* HLO  = (unsigned short*)ws; ws += (size_t)NB * 512 * 2;
  unsigned short* H2   = (unsigned short*)ws; ws += (size_t)NB * 512 * 2;
  unsigned short* RZ   = (unsigned short*)ws; ws += (size_t)NB * ND * 2;
  int* FCNT = (int*)ws; ws += 256;                 // keep alignment
  int* FLST = (int*)ws; ws += (size_t)FLAG_CAP * 4;
  double* Hd = (double*)ws; ws += (size_t)FLAG_CAP * 512 * 8;   // 16.8 MB

  // merged weight conversion (+ zero padding + flag-counter zero)
  k_prep<<<2048, 256, 0, stream>>>(enc_w1, W1HI, W1LO, enc_w2, W2HI, W2LO,
                                   dec_w1, DW1, dec_w2, DW2, FCNT);

  // GEMM1: h = relu(x @ w1^T + b1), split 3-pass, A = f32 x split in-kernel, BK=64
  dim3 g1(NB / 128, 4);
  k_gemm<4, 128, 4, true, true, 1, 64><<<g1, 256, 0, stream>>>(
      nullptr, nullptr, x, W1HI, W1LO, enc_b1, 500, HHI, HLO, DIN, 2048, 512, 512);
  // GEMM2: z = h @ w2^T + b2, split 3-pass, f32 out; BM=64, BK=32
  dim3 g2(NB / 64, 1);
  k_gemm<2, 64, 2, true, false, 0, 32><<<g2, 256, 0, stream>>>(
      HHI, HLO, nullptr, W2HI, W2LO, enc_b2, 64, z_out, nullptr, 512, 512, 64, 64);
  // clustering (+ flip-risk flagging)
  k_cluster<<<256, 256, 0, stream>>>(z_out, mu, g_out, q_out, FCNT, FLST);
  // exact f64 refinement, two phases
  dim3 gh(FLAG_CAP / 2, 8);
  k_ref_h<<<gh, 512, 0, stream>>>(x, enc_w1, enc_b1, FCNT, FLST, Hd);
  k_ref_zq<<<FLAG_CAP / 8, 512, 0, stream>>>(enc_w2, enc_b2, mu, Hd, FCNT, FLST, q_out);
  // fc0
  k_fc0<<<256, 256, 0, stream>>>(z_out, q_out, fc0_w, fc0_b, RZ);
  // GEMM4: h2 = relu(recon_z @ dec_w1^T + b1), bf16; BK=32
  dim3 g4(NB / 128, 4);
  k_gemm<4, 128, 4, false, false, 2, 32><<<g4, 256, 0, stream>>>(
      RZ, nullptr, nullptr, DW1, nullptr, dec_b1, 500, H2, nullptr, 64, 64, 512, 512);
  // GEMM5: recon_x = sigmoid(h2 @ dec_w2^T + b2), bf16, f32 masked store; BK=32
  dim3 g5(NB / 128, 16);
  k_gemm<4, 128, 4, false, false, 3, 32><<<g5, 256, 0, stream>>>(
      H2, nullptr, nullptr, DW2, nullptr, dec_b2, 2000, rx_out, nullptr, 512, 512, 2000, 2000);
}

// Round 14
// 356.753 us; speedup vs baseline: 1.2473x; 1.0449x over previous
//
#include <hip/hip_runtime.h>
#include <stdint.h>
#include <math.h>

#define NB   16384   // batch
#define DIN  2000
#define NH   500     // hidden
#define ND   64      // dim
#define NKC  256     // clusters

#define FLAG_CAP 4096
#define GAP_THR  0.002f  // sum-of-squares units; split-path dist noise ~1e-4 -> ~20x margin

typedef __attribute__((ext_vector_type(4))) float  f32x4;
typedef __attribute__((ext_vector_type(4))) double f64x4;
typedef __attribute__((ext_vector_type(8))) short  s16x8;

// ---------- bf16 helpers ----------
__device__ __forceinline__ unsigned short f2bf_rne(float v) {
  unsigned int u = __float_as_uint(v);
  u += 0x7fffu + ((u >> 16) & 1u);
  return (unsigned short)(u >> 16);
}
// fast split: hi = truncate-to-bf16, lo = truncate(v - hi). total rel err <= 2^-15
__device__ __forceinline__ void split_rtz(float v, unsigned short &hi, unsigned short &lo) {
  unsigned int u = __float_as_uint(v);
  hi = (unsigned short)(u >> 16);
  float r = v - __uint_as_float(u & 0xffff0000u);
  lo = (unsigned short)(__float_as_uint(r) >> 16);
}

// ---------- async global->LDS, 16B per lane ----------
typedef const __attribute__((address_space(1))) void* gas_t;
typedef __attribute__((address_space(3))) void* las_t;
__device__ __forceinline__ void gl_lds16(const void* g, void* l) {
  __builtin_amdgcn_global_load_lds((gas_t)g, (las_t)l, 16, 0, 0);
}

// ---------- split-pad body (grid-stride within segment) ----------
__device__ __forceinline__ void split_pad_seg(const float* __restrict__ in,
                                              unsigned short* __restrict__ hi,
                                              unsigned short* __restrict__ lo,
                                              int R, int C, int Cp, int total,
                                              int bseg, int nblk) {
  int stride = nblk * 256;
  for (int idx = bseg * 256 + threadIdx.x; idx < total; idx += stride) {
    int r = idx / Cp, c = idx - r * Cp;
    float v = (r < R && c < C) ? in[(size_t)r * C + c] : 0.f;
    if (lo) {
      unsigned short h, l; split_rtz(v, h, l);
      hi[idx] = h; lo[idx] = l;
    } else {
      hi[idx] = f2bf_rne(v);
    }
  }
}

// ---------- merged prep: 4 weight converts + flag-counter zero ----------
// partition: [0,1024) w1 | [1024,1088) w2 | [1088,1152) dec_w1 | [1152,2048) dec_w2
__global__ __launch_bounds__(256) void k_prep(const float* __restrict__ w1,
                                              unsigned short* __restrict__ W1HI,
                                              unsigned short* __restrict__ W1LO,
                                              const float* __restrict__ w2,
                                              unsigned short* __restrict__ W2HI,
                                              unsigned short* __restrict__ W2LO,
                                              const float* __restrict__ dw1,
                                              unsigned short* __restrict__ DW1,
                                              const float* __restrict__ dw2,
                                              unsigned short* __restrict__ DW2,
                                              int* __restrict__ fcnt)
{
  const int b = blockIdx.x;
  if (b == 0 && threadIdx.x == 0) *fcnt = 0;
  if (b < 1024) {
    split_pad_seg(w1, W1HI, W1LO, 500, 2000, 2048, 512 * 2048, b, 1024);
  } else if (b < 1088) {
    split_pad_seg(w2, W2HI, W2LO, 64, 500, 512, 64 * 512, b - 1024, 64);
  } else if (b < 1152) {
    split_pad_seg(dw1, DW1, nullptr, 500, 64, 64, 512 * 64, b - 1088, 64);
  } else {
    split_pad_seg(dw2, DW2, nullptr, 2000, 500, 512, 2048 * 512, b - 1152, 896);
  }
}

// ---------- GEMM: C[M,N] = A[M,K] * B[N,K]^T (+bias, epilogue) ----------
// BM = WR*32. BK in {32,64}: chunk swizzle ch ^= (row>>1)&(BK/8-1).
// AF32: A read f32 + split in-register to LDS (same linear layout as gl_lds).
// EPI: 0 = f32 store, 1 = relu+split bf16, 2 = relu+bf16, 3 = sigmoid+f32
template<int WR, int BN, int WC, bool SPLIT, bool AF32, int EPI, int BK>
__global__ __launch_bounds__(256) void k_gemm(
    const unsigned short* __restrict__ Ahi, const unsigned short* __restrict__ Alo,
    const float* __restrict__ Axf,
    const unsigned short* __restrict__ Bhi, const unsigned short* __restrict__ Blo,
    const float* __restrict__ bias, int bias_n,
    void* __restrict__ out0, void* __restrict__ out1,
    int ldA, int K, int out_ld, int store_n)
{
  constexpr int BM  = WR * 32;
  constexpr int CPR = BK / 8;          // 16B chunks per row
  constexpr int ACH = BM * CPR;        // chunks per A tile
  constexpr int BCH = BN * CPR;
  __shared__ unsigned short aHi[BM * BK];
  __shared__ unsigned short aLo[SPLIT ? BM * BK : 8];
  __shared__ unsigned short bHi[BN * BK];
  __shared__ unsigned short bLo[SPLIT ? BN * BK : 8];

  const int tid  = threadIdx.x;
  const int lane = tid & 63, wave = tid >> 6;
  const int wm = wave >> 1, wn = wave & 1;
  const int lr = lane & 15, lg = lane >> 4;
  const int swz = (lr >> 1) & (CPR - 1);    // read-side chunk XOR (const per lane)
  const int m0 = blockIdx.x * BM, n0 = blockIdx.y * BN;

  f32x4 acc[WR][WC];
#pragma unroll
  for (int i = 0; i < WR; ++i)
#pragma unroll
    for (int j = 0; j < WC; ++j)
#pragma unroll
      for (int r = 0; r < 4; ++r) acc[i][j][r] = 0.f;

  for (int k0 = 0; k0 < K; k0 += BK) {
    // ---- stage A: linear LDS dest, swizzled global source chunk ----
#pragma unroll
    for (int j = 0; j < ACH / 256; ++j) {
      int c = (j * 4 + wave) * 64 + lane;
      int row = c / CPR;
      int ch = (c & (CPR - 1)) ^ ((row >> 1) & (CPR - 1));
      if constexpr (AF32) {
        int col = k0 + ch * 8;               // 8-aligned; DIN%8==0 -> chunk all-valid or all-pad
        s16x8 h8 = {0,0,0,0,0,0,0,0}, l8 = {0,0,0,0,0,0,0,0};
        if (col < DIN) {
          const float* src = Axf + (size_t)(m0 + row) * ldA + col;
          f32x4 v0 = *(const f32x4*)src;
          f32x4 v1 = *(const f32x4*)(src + 4);
#pragma unroll
          for (int q = 0; q < 4; ++q) {
            unsigned short h, l;
            split_rtz(v0[q], h, l); h8[q] = (short)h; l8[q] = (short)l;
            split_rtz(v1[q], h, l); h8[4 + q] = (short)h; l8[4 + q] = (short)l;
          }
        }
        *(s16x8*)&aHi[c * 8] = h8;
        *(s16x8*)&aLo[c * 8] = l8;
      } else {
        const unsigned short* sA = Ahi + (size_t)(m0 + row) * ldA + k0 + ch * 8;
        gl_lds16(sA, (char*)aHi + c * 16);
        if constexpr (SPLIT) {
          const unsigned short* sL = Alo + (size_t)(m0 + row) * ldA + k0 + ch * 8;
          gl_lds16(sL, (char*)aLo + c * 16);
        }
      }
    }
    // ---- stage B (always bf16 via gl_lds, pre-padded buffers) ----
#pragma unroll
    for (int j = 0; j < BCH / 256; ++j) {
      int c = (j * 4 + wave) * 64 + lane;
      int row = c / CPR;
      int ch = (c & (CPR - 1)) ^ ((row >> 1) & (CPR - 1));
      const unsigned short* sB = Bhi + (size_t)(n0 + row) * K + k0 + ch * 8;
      gl_lds16(sB, (char*)bHi + c * 16);
      if constexpr (SPLIT) {
        const unsigned short* sL = Blo + (size_t)(n0 + row) * K + k0 + ch * 8;
        gl_lds16(sL, (char*)bLo + c * 16);
      }
    }
    __syncthreads();   // drains vmcnt + lgkmcnt before barrier

    // ---- fragments (swizzled ds_read) + MFMA, one sub-step per 32 of K ----
#pragma unroll
    for (int kk = 0; kk < BK / 32; ++kk) {
      const int fch = ((lg + 4 * kk) ^ swz) << 3;   // ushort offset of lane's k-chunk
      s16x8 ah[WR], bh[WC];
#pragma unroll
      for (int i = 0; i < WR; ++i)
        ah[i] = *(const s16x8*)&aHi[(wm * (WR * 16) + i * 16 + lr) * BK + fch];
#pragma unroll
      for (int j = 0; j < WC; ++j)
        bh[j] = *(const s16x8*)&bHi[(wn * (WC * 16) + j * 16 + lr) * BK + fch];
      if constexpr (SPLIT) {
        s16x8 al[WR], bl[WC];
#pragma unroll
        for (int i = 0; i < WR; ++i)
          al[i] = *(const s16x8*)&aLo[(wm * (WR * 16) + i * 16 + lr) * BK + fch];
#pragma unroll
        for (int j = 0; j < WC; ++j)
          bl[j] = *(const s16x8*)&bLo[(wn * (WC * 16) + j * 16 + lr) * BK + fch];
#pragma unroll
        for (int i = 0; i < WR; ++i)
#pragma unroll
          for (int j = 0; j < WC; ++j) {
            acc[i][j] = __builtin_amdgcn_mfma_f32_16x16x32_bf16(ah[i], bh[j], acc[i][j], 0, 0, 0);
            acc[i][j] = __builtin_amdgcn_mfma_f32_16x16x32_bf16(ah[i], bl[j], acc[i][j], 0, 0, 0);
            acc[i][j] = __builtin_amdgcn_mfma_f32_16x16x32_bf16(al[i], bh[j], acc[i][j], 0, 0, 0);
          }
      } else {
#pragma unroll
        for (int i = 0; i < WR; ++i)
#pragma unroll
          for (int j = 0; j < WC; ++j)
            acc[i][j] = __builtin_amdgcn_mfma_f32_16x16x32_bf16(ah[i], bh[j], acc[i][j], 0, 0, 0);
      }
    }
    __syncthreads();
  }

  // ---- epilogue: C/D layout col=lane&15, row=(lane>>4)*4+reg ----
#pragma unroll
  for (int i = 0; i < WR; ++i) {
    int grow = m0 + wm * (WR * 16) + i * 16 + lg * 4;
#pragma unroll
    for (int j = 0; j < WC; ++j) {
      int gcol = n0 + wn * (WC * 16) + j * 16 + lr;
      float bv = (gcol < bias_n) ? bias[gcol] : 0.f;
      f32x4 v = acc[i][j];
#pragma unroll
      for (int r = 0; r < 4; ++r) {
        float val = v[r] + bv;
        int rr = grow + r;
        if constexpr (EPI == 0) {
          if (gcol < store_n) ((float*)out0)[(size_t)rr * out_ld + gcol] = val;
        } else if constexpr (EPI == 1) {
          val = fmaxf(val, 0.f);
          unsigned short h, l; split_rtz(val, h, l);
          ((unsigned short*)out0)[(size_t)rr * out_ld + gcol] = h;
          ((unsigned short*)out1)[(size_t)rr * out_ld + gcol] = l;
        } else if constexpr (EPI == 2) {
          val = fmaxf(val, 0.f);
          ((unsigned short*)out0)[(size_t)rr * out_ld + gcol] = f2bf_rne(val);
        } else {
          val = 1.f / (1.f + expf(-val));
          if (gcol < store_n) ((float*)out0)[(size_t)rr * out_ld + gcol] = val;
        }
      }
    }
  }
}

// ---------- fused GEMM2 + clustering ----------
// z = h @ w2^T + b2 (split 3-pass, BM=BN=64, BK=64, one block = 64 complete rows),
// then in-block: dists vs mu, gamma softmax, argmin -> quantized, flag close rows.
__global__ __launch_bounds__(256) void k_gemm2c(
    const unsigned short* __restrict__ Ahi, const unsigned short* __restrict__ Alo,
    const unsigned short* __restrict__ Bhi, const unsigned short* __restrict__ Blo,
    const float* __restrict__ bias,
    const float* __restrict__ mu,
    float* __restrict__ z, float* __restrict__ gamma, float* __restrict__ quant,
    int* __restrict__ flag_cnt, int* __restrict__ flag_list)
{
  constexpr int BM = 64, BN = 64, BK = 64, CPR = 8, WR = 2, WC = 2, K = 512;
  __shared__ unsigned short aHi[BM * BK];   // 8 KB
  __shared__ unsigned short aLo[BM * BK];
  __shared__ unsigned short bHi[BN * BK];
  __shared__ unsigned short bLo[BN * BK];
  __shared__ float zl[64][64];              // 16 KB
  __shared__ float mu_t[ND][NKC];           // 64 KB (same layout as proven k_cluster)

  const int tid  = threadIdx.x;
  const int lane = tid & 63, wave = tid >> 6;
  const int wm = wave >> 1, wn = wave & 1;
  const int lr = lane & 15, lg = lane >> 4;
  const int swz = (lr >> 1) & (CPR - 1);
  const int m0 = blockIdx.x * BM;

  // stage mu transposed (proven k_cluster layout)
  for (int i = tid; i < NKC * ND; i += 256) {
    mu_t[i & 63][i >> 6] = mu[i];
  }

  f32x4 acc[WR][WC];
#pragma unroll
  for (int i = 0; i < WR; ++i)
#pragma unroll
    for (int j = 0; j < WC; ++j)
#pragma unroll
      for (int r = 0; r < 4; ++r) acc[i][j][r] = 0.f;

  for (int k0 = 0; k0 < K; k0 += BK) {
#pragma unroll
    for (int j = 0; j < (BM * CPR) / 256; ++j) {
      int c = (j * 4 + wave) * 64 + lane;
      int row = c / CPR;
      int ch = (c & (CPR - 1)) ^ ((row >> 1) & (CPR - 1));
      gl_lds16(Ahi + (size_t)(m0 + row) * K + k0 + ch * 8, (char*)aHi + c * 16);
      gl_lds16(Alo + (size_t)(m0 + row) * K + k0 + ch * 8, (char*)aLo + c * 16);
    }
#pragma unroll
    for (int j = 0; j < (BN * CPR) / 256; ++j) {
      int c = (j * 4 + wave) * 64 + lane;
      int row = c / CPR;
      int ch = (c & (CPR - 1)) ^ ((row >> 1) & (CPR - 1));
      gl_lds16(Bhi + (size_t)row * K + k0 + ch * 8, (char*)bHi + c * 16);
      gl_lds16(Blo + (size_t)row * K + k0 + ch * 8, (char*)bLo + c * 16);
    }
    __syncthreads();
#pragma unroll
    for (int kk = 0; kk < BK / 32; ++kk) {
      const int fch = ((lg + 4 * kk) ^ swz) << 3;
      s16x8 ah[WR], bh[WC], al[WR], bl[WC];
#pragma unroll
      for (int i = 0; i < WR; ++i) {
        ah[i] = *(const s16x8*)&aHi[(wm * 32 + i * 16 + lr) * BK + fch];
        al[i] = *(const s16x8*)&aLo[(wm * 32 + i * 16 + lr) * BK + fch];
      }
#pragma unroll
      for (int j = 0; j < WC; ++j) {
        bh[j] = *(const s16x8*)&bHi[(wn * 32 + j * 16 + lr) * BK + fch];
        bl[j] = *(const s16x8*)&bLo[(wn * 32 + j * 16 + lr) * BK + fch];
      }
#pragma unroll
      for (int i = 0; i < WR; ++i)
#pragma unroll
        for (int j = 0; j < WC; ++j) {
          acc[i][j] = __builtin_amdgcn_mfma_f32_16x16x32_bf16(ah[i], bh[j], acc[i][j], 0, 0, 0);
          acc[i][j] = __builtin_amdgcn_mfma_f32_16x16x32_bf16(ah[i], bl[j], acc[i][j], 0, 0, 0);
          acc[i][j] = __builtin_amdgcn_mfma_f32_16x16x32_bf16(al[i], bh[j], acc[i][j], 0, 0, 0);
        }
    }
    __syncthreads();
  }

  // epilogue: + bias, store z (global + LDS)
#pragma unroll
  for (int i = 0; i < WR; ++i) {
    int lrow = wm * 32 + i * 16 + lg * 4;
#pragma unroll
    for (int j = 0; j < WC; ++j) {
      int col = wn * 32 + j * 16 + lr;
      float bv = bias[col];
      f32x4 v = acc[i][j];
#pragma unroll
      for (int r = 0; r < 4; ++r) {
        float val = v[r] + bv;
        z[(size_t)(m0 + lrow + r) * ND + col] = val;
        zl[lrow + r][col] = val;
      }
    }
  }
  __syncthreads();

  // ---- clustering on the 64 in-LDS rows (verbatim k_cluster math) ----
  for (int it = 0; it < 4; ++it) {
    int r4 = wave * 16 + it * 4;   // local row base
    float zr[4];
#pragma unroll
    for (int r = 0; r < 4; ++r) zr[r] = zl[r4 + r][lane];
    float ds[4][4];
#pragma unroll
    for (int r = 0; r < 4; ++r)
#pragma unroll
      for (int g = 0; g < 4; ++g) ds[r][g] = 0.f;
    for (int d = 0; d < ND; ++d) {
      f32x4 m4 = *(const f32x4*)&mu_t[d][lane << 2];
#pragma unroll
      for (int r = 0; r < 4; ++r) {
        float zd = __shfl(zr[r], d, 64);
#pragma unroll
        for (int g = 0; g < 4; ++g) {
          float t = zd - m4[g];
          ds[r][g] = fmaf(t, t, ds[r][g]);
        }
      }
    }
#pragma unroll
    for (int r = 0; r < 4; ++r) {
      int row = m0 + r4 + r;
      float bd = ds[r][0]; int bk = (lane << 2);
#pragma unroll
      for (int g = 1; g < 4; ++g)
        if (ds[r][g] < bd) { bd = ds[r][g]; bk = (lane << 2) + g; }
      for (int off = 1; off < 64; off <<= 1) {
        float od = __shfl_xor(bd, off, 64);
        int   ok = __shfl_xor(bk, off, 64);
        if (od < bd || (od == bd && ok < bk)) { bd = od; bk = ok; }  // first-index tie-break
      }
      float sb = 3.4e38f;
#pragma unroll
      for (int g = 0; g < 4; ++g) {
        int kk = (lane << 2) + g;
        if (kk != bk) sb = fminf(sb, ds[r][g]);
      }
      for (int off = 1; off < 64; off <<= 1) sb = fminf(sb, __shfl_xor(sb, off, 64));
      if (lane == 0 && (sb - bd) < GAP_THR) {
        int p = atomicAdd(flag_cnt, 1);
        if (p < FLAG_CAP) flag_list[p] = row;
      }
      const float cc = -5.f / 64.f;   // DELTA / dim (z_dist is a mean)
      float e[4], s = 0.f;
#pragma unroll
      for (int g = 0; g < 4; ++g) { e[g] = expf(cc * (ds[r][g] - bd)); s += e[g]; }
      for (int off = 1; off < 64; off <<= 1) s += __shfl_xor(s, off, 64);
      float inv = 1.f / s;
      f32x4 g4 = { e[0] * inv, e[1] * inv, e[2] * inv, e[3] * inv };
      *(f32x4*)&gamma[(size_t)row * NKC + (lane << 2)] = g4;
      quant[(size_t)row * ND + lane] = mu[(size_t)bk * ND + lane];
    }
  }
}

// ---------- refine phase A: Hd[pos][512] = relu(x @ w1^T + b1) in f64 ----------
__global__ __launch_bounds__(512) void k_ref_h(const float* __restrict__ x,
                                               const float* __restrict__ w1,
                                               const float* __restrict__ b1,
                                               const int* __restrict__ flag_cnt,
                                               const int* __restrict__ flag_list,
                                               double* __restrict__ Hd)
{
  __shared__ __align__(16) double xs[2][DIN];   // 32000 B
  __shared__ int rows_s[2];

  int cnt = *flag_cnt; if (cnt > FLAG_CAP) cnt = FLAG_CAP;
  const int base = blockIdx.x * 2;
  if (base >= cnt) return;
  const int tid = threadIdx.x, lane = tid & 63, wave = tid >> 6;
  const int ybase = blockIdx.y * 64;
  const int yend  = (ybase + 64 < NH) ? (ybase + 64) : NH;   // last tile: 52 rows

  if (tid < 2) rows_s[tid] = flag_list[(base + tid < cnt) ? (base + tid) : base];
  __syncthreads();
  const int row0 = rows_s[0], row1 = rows_s[1];

  // stage x rows (coalesced), convert to f64 once
  for (int c = tid; c < DIN; c += 512) {
    xs[0][c] = (double)x[(size_t)row0 * DIN + c];
    xs[1][c] = (double)x[(size_t)row1 * DIN + c];
  }
  __syncthreads();

  // h-rows of this tile; 4 per wave-iter, lanes k-parallel (proven v3 inner)
  for (int hr0 = ybase + wave * 4; hr0 < yend; hr0 += 32) {
    double a[4][2];
#pragma unroll
    for (int r = 0; r < 4; ++r) { a[r][0] = 0.0; a[r][1] = 0.0; }
    for (int c = lane; c < DIN / 4; c += 64) {          // 500 f32x4 chunks
      f64x4 x0 = *(const f64x4*)(&xs[0][c * 4]);
      f64x4 x1 = *(const f64x4*)(&xs[1][c * 4]);
#pragma unroll
      for (int r = 0; r < 4; ++r) {
        f32x4 w4 = *(const f32x4*)(w1 + (size_t)(hr0 + r) * DIN + c * 4);
#pragma unroll
        for (int j = 0; j < 4; ++j) {
          double w = (double)w4[j];
          a[r][0] = fma(w, x0[j], a[r][0]);
          a[r][1] = fma(w, x1[j], a[r][1]);
        }
      }
    }
#pragma unroll
    for (int off = 32; off; off >>= 1)
#pragma unroll
      for (int r = 0; r < 4; ++r) {
        a[r][0] += __shfl_xor(a[r][0], off, 64);
        a[r][1] += __shfl_xor(a[r][1], off, 64);
      }
    if (lane == 0) {
#pragma unroll
      for (int r = 0; r < 4; ++r) {
        double b = (double)b1[hr0 + r];
        double v0 = a[r][0] + b, v1 = a[r][1] + b;
        Hd[(size_t)(base + 0) * 512 + hr0 + r] = v0 > 0.0 ? v0 : 0.0;
        Hd[(size_t)(base + 1) * 512 + hr0 + r] = v1 > 0.0 ? v1 : 0.0;
      }
    }
  }
}

// ---------- refine phase B: z = Hd @ w2^T + b2 (f64), dist, argmin, write quant ----------
__global__ __launch_bounds__(512) void k_ref_zq(const float* __restrict__ w2,
                                                const float* __restrict__ b2,
                                                const float* __restrict__ mu,
                                                const double* __restrict__ Hd,
                                                const int* __restrict__ flag_cnt,
                                                const int* __restrict__ flag_list,
                                                float* __restrict__ quant)
{
  __shared__ double hsl[8][NH];     // 32 KB
  __shared__ float  mu_t[ND][NKC + 1];  // 65.8 KB, transposed, padded
  __shared__ double zs[8][ND];      // 4 KB
  __shared__ int    rows_s[8];

  int cnt = *flag_cnt; if (cnt > FLAG_CAP) cnt = FLAG_CAP;
  const int base = blockIdx.x * 8;
  if (base >= cnt) return;
  const int tid = threadIdx.x, lane = tid & 63, wave = tid >> 6;

  if (tid < 8) rows_s[tid] = flag_list[(base + tid < cnt) ? (base + tid) : base];
  // stage mu transposed
  for (int i = tid; i < NKC * ND; i += 512) {
    mu_t[i & 63][i >> 6] = mu[i];
  }
  // stage Hd rows: wave w <-> slot w
  {
    int pos = (base + wave < cnt) ? (base + wave) : base;
    const double* hr = Hd + (size_t)pos * 512;
    for (int i = lane; i < NH; i += 64) hsl[wave][i] = hr[i];
  }
  __syncthreads();

  // ---- z: 512 (row,dim) pairs; per wave 16 groups of 4 interleaved reductions ----
  for (int g4 = 0; g4 < 16; ++g4) {
    double a[4] = {0.0, 0.0, 0.0, 0.0};
    int q[4];
#pragma unroll
    for (int u = 0; u < 4; ++u) q[u] = g4 * 32 + u * 8 + wave;
    for (int i = lane; i < NH; i += 64) {
#pragma unroll
      for (int u = 0; u < 4; ++u) {
        int r = q[u] >> 6, d = q[u] & 63;
        a[u] = fma(hsl[r][i], (double)w2[(size_t)d * NH + i], a[u]);
      }
    }
#pragma unroll
    for (int off = 32; off; off >>= 1)
#pragma unroll
      for (int u = 0; u < 4; ++u) a[u] += __shfl_xor(a[u], off, 64);
    if (lane == 0) {
#pragma unroll
      for (int u = 0; u < 4; ++u) {
        int r = q[u] >> 6, d = q[u] & 63;
        zs[r][d] = a[u] + (double)b2[d];
      }
    }
  }
  __syncthreads();

  // ---- dist + argmin: wave <-> row; lane l owns clusters l, l+64, l+128, l+192 ----
  {
    double bd = 1.0e300; int bk = 0;
#pragma unroll
    for (int g = 0; g < 4; ++g) {
      int k = g * 64 + lane;
      double dist = 0.0;
#pragma unroll 8
      for (int d = 0; d < ND; ++d) {
        double t = zs[wave][d] - (double)mu_t[d][k];
        dist = fma(t, t, dist);
      }
      if (g == 0 || dist < bd) { bd = dist; bk = k; }   // k increases: strict < = first-index
    }
    for (int off = 1; off < 64; off <<= 1) {
      double od = __shfl_xor(bd, off, 64);
      int    ok = __shfl_xor(bk, off, 64);
      if (od < bd || (od == bd && ok < bk)) { bd = od; bk = ok; }
    }
    quant[(size_t)rows_s[wave] * ND + lane] = mu[(size_t)bk * ND + lane];
  }
}

// ---------- fc0: recon_z = [z | quantized] @ fc0_w^T + fc0_b  (f32, store bf16) ----------
__global__ __launch_bounds__(256) void k_fc0(const float* __restrict__ z, const float* __restrict__ quant,
                                             const float* __restrict__ W, const float* __restrict__ b,
                                             unsigned short* __restrict__ rz)
{
  __shared__ float Wt[2 * ND][ND];   // [128][64] transposed, 32 KB
  for (int i = threadIdx.x; i < ND * 2 * ND; i += 256) {
    int j = i >> 7;      // output index
    int ii = i & 127;    // input index
    Wt[ii][j] = W[i];
  }
  __syncthreads();
  const int lane = threadIdx.x & 63, wave = threadIdx.x >> 6;
  float bj = b[lane];
  for (int row = blockIdx.x * 4 + wave; row < NB; row += gridDim.x * 4) {
    float zv = z[(size_t)row * ND + lane];
    float qv = quant[(size_t)row * ND + lane];
    float acc = bj;
#pragma unroll 8
    for (int i = 0; i < ND; ++i) {
      acc = fmaf(__shfl(zv, i, 64), Wt[i][lane], acc);
      acc = fmaf(__shfl(qv, i, 64), Wt[ND + i][lane], acc);
    }
    rz[(size_t)row * ND + lane] = f2bf_rne(acc);
  }
}

// ---------- host ----------
extern "C" void kernel_launch(void* const* d_in, const int* in_sizes, int n_in,
                              void* d_out, int out_size, void* d_ws, size_t ws_size,
                              hipStream_t stream)
{
  const float* x      = (const float*)d_in[2];
  const float* mu     = (const float*)d_in[3];
  const float* enc_w1 = (const float*)d_in[4];
  const float* enc_b1 = (const float*)d_in[5];
  const float* enc_w2 = (const float*)d_in[6];
  const float* enc_b2 = (const float*)d_in[7];
  const float* fc0_w  = (const float*)d_in[8];
  const float* fc0_b  = (const float*)d_in[9];
  const float* dec_w1 = (const float*)d_in[10];
  const float* dec_b1 = (const float*)d_in[11];
  const float* dec_w2 = (const float*)d_in[12];
  const float* dec_b2 = (const float*)d_in[13];

  float* z_out  = (float*)d_out;
  float* q_out  = z_out + (size_t)NB * ND;
  float* g_out  = q_out + (size_t)NB * ND;
  float* rx_out = g_out + (size_t)NB * NKC;

  char* ws = (char*)d_ws;
  unsigned short* W1HI = (unsigned short*)ws; ws += (size_t)512 * 2048 * 2;
  unsigned short* W1LO = (unsigned short*)ws; ws += (size_t)512 * 2048 * 2;
  unsigned short* W2HI = (unsigned short*)ws; ws += (size_t)64 * 512 * 2;
  unsigned short* W2LO = (unsigned short*)ws; ws += (size_t)64 * 512 * 2;
  unsigned short* DW1  = (unsigned short*)ws; ws += (size_t)512 * 64 * 2;
  unsigned short* DW2  = (unsigned short*)ws; ws += (size_t)2048 * 512 * 2;
  unsigned short* HHI  = (unsigned short*)ws; ws += (size_t)NB * 512 * 2;
  unsigned short* HLO  = (unsigned short*)ws; ws += (size_t)NB * 512 * 2;
  unsigned short* H2   = (unsigned short*)ws; ws += (size_t)NB * 512 * 2;
  unsigned short* RZ   = (unsigned short*)ws; ws += (size_t)NB * ND * 2;
  int* FCNT = (int*)ws; ws += 256;                 // keep alignment
  int* FLST = (int*)ws; ws += (size_t)FLAG_CAP * 4;
  double* Hd = (double*)ws; ws += (size_t)FLAG_CAP * 512 * 8;   // 16.8 MB

  // merged weight conversion (+ zero padding + flag-counter zero)
  k_prep<<<2048, 256, 0, stream>>>(enc_w1, W1HI, W1LO, enc_w2, W2HI, W2LO,
                                   dec_w1, DW1, dec_w2, DW2, FCNT);

  // GEMM1: h = relu(x @ w1^T + b1), split 3-pass, A = f32 x split in-kernel, BK=64
  dim3 g1(NB / 128, 4);
  k_gemm<4, 128, 4, true, true, 1, 64><<<g1, 256, 0, stream>>>(
      nullptr, nullptr, x, W1HI, W1LO, enc_b1, 500, HHI, HLO, DIN, 2048, 512, 512);
  // fused GEMM2 + clustering (z, gamma, quantized, flip-risk flags)
  k_gemm2c<<<NB / 64, 256, 0, stream>>>(HHI, HLO, W2HI, W2LO, enc_b2, mu,
                                        z_out, g_out, q_out, FCNT, FLST);
  // exact f64 refinement, two phases
  dim3 gh(FLAG_CAP / 2, 8);
  k_ref_h<<<gh, 512, 0, stream>>>(x, enc_w1, enc_b1, FCNT, FLST, Hd);
  k_ref_zq<<<FLAG_CAP / 8, 512, 0, stream>>>(enc_w2, enc_b2, mu, Hd, FCNT, FLST, q_out);
  // fc0
  k_fc0<<<256, 256, 0, stream>>>(z_out, q_out, fc0_w, fc0_b, RZ);
  // GEMM4: h2 = relu(recon_z @ dec_w1^T + b1), bf16; BK=64 -> single K-phase
  dim3 g4(NB / 128, 4);
  k_gemm<4, 128, 4, false, false, 2, 64><<<g4, 256, 0, stream>>>(
      RZ, nullptr, nullptr, DW1, nullptr, dec_b1, 500, H2, nullptr, 64, 64, 512, 512);
  // GEMM5: recon_x = sigmoid(h2 @ dec_w2^T + b2), bf16, f32 masked store; BK=64
  dim3 g5(NB / 128, 16);
  k_gemm<4, 128, 4, false, false, 3, 64><<<g5, 256, 0, stream>>>(
      H2, nullptr, nullptr, DW2, nullptr, dec_b2, 2000, rx_out, nullptr, 512, 512, 2000, 2000);
}